// Round 3
// baseline (384.363 us; speedup 1.0000x reference)
//
#include <hip/hip_runtime.h>
#include <math.h>

// Problem constants
#define B_    1024
#define D_    768
#define C_    150
#define P_    64
#define TWOD  1536
#define NCLS  151   // C+1
#define NCOL  215   // 151 seen/unseen + 64 u-projection cols

// fused_tile config: 128b x 64c tile, 8x4 per thread, e split 16 ways
#define ECHUNKS 16
#define ECHUNK  96    // TWOD / ECHUNKS
#define ESTEP   16
#define XSTR    132   // LDS stride for x tile (16B-aligned rows, conflict-free)
#define MSTR    68    // LDS stride for m/w tiles

// Workspace layout (float offsets)
#define OFF_MH     0
#define OFF_XH     (OFF_MH + C_ * TWOD)             // 230400
#define OFF_LOGITS (OFF_XH + B_ * TWOD)             // 1803264
#define OFF_U      (OFF_LOGITS + B_ * NCLS)
#define OFF_SQN    (OFF_U + B_ * P_)
#define OFF_PART   (OFF_SQN + B_)                   // 8 floats
#define OFF_XBF    (OFF_PART + 8)                   // even -> 8B aligned
#define OFF_MEMBF  (OFF_XBF + (B_ * D_) / 2)
#define OFF_WBF    (OFF_MEMBF + (C_ * D_) / 2)
// end: OFF_WBF + TWOD*TWOD/2 ~ 3.65M floats ~ 14.6 MB

typedef __bf16 bfx8 __attribute__((ext_vector_type(8)));
typedef float  f32x4 __attribute__((ext_vector_type(4)));

// ---------------------------------------------------------------------------
// K0: fp32 -> bf16 (RNE) conversion for x, mem, fc_w. One float4 per thread.
// ---------------------------------------------------------------------------
#define X4   (B_ * D_ / 4)          // 196608
#define MEM4 (C_ * D_ / 4)          // 28800
#define W4   (TWOD * TWOD / 4)      // 589824
#define TOT4 (X4 + MEM4 + W4)

__device__ inline ushort f2bf(float f) {
    union { float f; unsigned u; } c; c.f = f;
    unsigned r = c.u + 0x7fffu + ((c.u >> 16) & 1u);
    return (ushort)(r >> 16);
}

__global__ __launch_bounds__(256) void to_bf16(
    const float* __restrict__ x, const float* __restrict__ mem,
    const float* __restrict__ w,
    ushort* __restrict__ xb, ushort* __restrict__ memb, ushort* __restrict__ wb)
{
    int i = blockIdx.x * 256 + threadIdx.x;
    if (i >= TOT4) return;
    const float* src; ushort* dst; int off;
    if (i < X4)            { src = x;   dst = xb;   off = i; }
    else if (i < X4 + MEM4){ src = mem; dst = memb; off = i - X4; }
    else                   { src = w;   dst = wb;   off = i - X4 - MEM4; }
    float4 v = ((const float4*)src)[off];
    ushort4 o;
    o.x = f2bf(v.x); o.y = f2bf(v.y); o.z = f2bf(v.z); o.w = f2bf(v.w);
    ((ushort4*)dst)[off] = o;
}

// ---------------------------------------------------------------------------
// K1/K2: bf16 MFMA GEMM (NT): Out[m,n] = sum_k A[m,k]*Bw[n,koff+k] (+bias[n])
// 128x128 tile, BK=32, 4 waves (2x2 of 64x64), mfma_f32_16x16x32_bf16.
// N must be a multiple of 128; M masked.
// ---------------------------------------------------------------------------
__global__ __launch_bounds__(256) void gemm_mfma(
    const ushort* __restrict__ A, int M, int lda,
    const ushort* __restrict__ Bw, int ldb, int koff,
    const float* __restrict__ bias,
    float* __restrict__ Out, int ldo, int K)
{
    __shared__ ushort As[128 * 32];
    __shared__ ushort Bs[128 * 32];
    const int t    = threadIdx.x;
    const int m0   = blockIdx.x * 128, n0 = blockIdx.y * 128;
    const int wave = t >> 6, lane = t & 63;
    const int wm   = (wave & 1) * 64, wn = (wave >> 1) * 64;
    const int fm   = lane & 15, quad = lane >> 4;

    f32x4 acc[4][4];
#pragma unroll
    for (int i = 0; i < 4; ++i)
#pragma unroll
        for (int j = 0; j < 4; ++j) acc[i][j] = (f32x4){0.f, 0.f, 0.f, 0.f};

    for (int k0 = 0; k0 < K; k0 += 32) {
        uint4 av[2], bv[2];
#pragma unroll
        for (int s = 0; s < 2; ++s) {
            int c = t + s * 256;
            int row = c >> 2, q = c & 3;
            int ar = m0 + row; ar = ar < M ? ar : (M - 1);
            av[s] = *(const uint4*)&A[(size_t)ar * lda + k0 + q * 8];
            bv[s] = *(const uint4*)&Bw[(size_t)(n0 + row) * ldb + koff + k0 + q * 8];
        }
        __syncthreads();   // previous step's frag reads complete
#pragma unroll
        for (int s = 0; s < 2; ++s) {
            int c = t + s * 256;
            int row = c >> 2, q = c & 3;
            *(uint4*)&As[row * 32 + q * 8] = av[s];
            *(uint4*)&Bs[row * 32 + q * 8] = bv[s];
        }
        __syncthreads();

        bfx8 af[4], bfr[4];
#pragma unroll
        for (int i = 0; i < 4; ++i) {
            af[i]  = *(const bfx8*)&As[(wm + i * 16 + fm) * 32 + quad * 8];
            bfr[i] = *(const bfx8*)&Bs[(wn + i * 16 + fm) * 32 + quad * 8];
        }
#pragma unroll
        for (int i = 0; i < 4; ++i)
#pragma unroll
            for (int j = 0; j < 4; ++j)
                acc[i][j] = __builtin_amdgcn_mfma_f32_16x16x32_bf16(
                    af[i], bfr[j], acc[i][j], 0, 0, 0);
    }

#pragma unroll
    for (int i = 0; i < 4; ++i)
#pragma unroll
        for (int j = 0; j < 4; ++j)
#pragma unroll
            for (int r = 0; r < 4; ++r) {
                int row = m0 + wm + i * 16 + quad * 4 + r;
                int col = n0 + wn + j * 16 + fm;
                if (row < M)
                    Out[(size_t)row * ldo + col] =
                        acc[i][j][r] + (bias ? bias[col] : 0.f);
            }
}

// ---------------------------------------------------------------------------
// K3: fused tile: out[b,c] = sum_e relu(xh[b,e] + m[c,e]) * w[c,e]
//   c <150: m=mh[c], w=p1 ; c==150: m=0, w=p1 ; c in [151,215): m=0, w=p2w
// 128b x 64c per block, 8x4 per thread, e split ECHUNKS ways (atomicAdd).
// ---------------------------------------------------------------------------
__global__ __launch_bounds__(256) void fused_tile(
    const float* __restrict__ xh, const float* __restrict__ mh,
    const float* __restrict__ p1w, const float* __restrict__ p1b,
    const float* __restrict__ p2w, const float* __restrict__ p2b,
    float* __restrict__ logits, float* __restrict__ u)
{
    __shared__ float xT[ESTEP * XSTR];
    __shared__ float mT[ESTEP * MSTR];
    __shared__ float wT[ESTEP * MSTR];

    const int t  = threadIdx.x;
    const int b0 = blockIdx.x * 128;
    const int c0 = blockIdx.y * 64;
    const int e0 = blockIdx.z * ECHUNK;
    const int tm = t & 15;      // b-group: 8 rows each
    const int tn = t >> 4;      // c-group: 4 cols each

    // staging roles
    const int xb  = t >> 1, xe0 = (t & 1) * 8;    // x: 8 e's for one b-row
    const int mc  = t >> 2, me0 = (t & 3) * 4;    // m/w: 4 e's for one c-col
    const int gc  = c0 + mc;
    const bool cseen = gc < C_;
    const bool cu    = (gc >= NCLS) && (gc < NCOL);
    const bool wval  = gc < NCOL;
    const float* xrow = xh + (size_t)(b0 + xb) * TWOD;
    const float* mrow = mh + (size_t)(cseen ? gc : 0) * TWOD;
    const float* wrow = cu ? (p2w + (size_t)(gc - NCLS) * TWOD) : p1w;

    float acc[8][4] = {};

    for (int es = 0; es < ECHUNK; es += ESTEP) {
        const int eb = e0 + es;
        float xv[8];
        *(float4*)&xv[0] = *(const float4*)&xrow[eb + xe0];
        *(float4*)&xv[4] = *(const float4*)&xrow[eb + xe0 + 4];
        float4 mv = cseen ? *(const float4*)&mrow[eb + me0]
                          : make_float4(0.f, 0.f, 0.f, 0.f);
        float4 wv = wval  ? *(const float4*)&wrow[eb + me0]
                          : make_float4(0.f, 0.f, 0.f, 0.f);
        __syncthreads();   // previous step's LDS reads complete
#pragma unroll
        for (int k = 0; k < 8; ++k) xT[(xe0 + k) * XSTR + xb] = xv[k];
        mT[(me0 + 0) * MSTR + mc] = mv.x; mT[(me0 + 1) * MSTR + mc] = mv.y;
        mT[(me0 + 2) * MSTR + mc] = mv.z; mT[(me0 + 3) * MSTR + mc] = mv.w;
        wT[(me0 + 0) * MSTR + mc] = wv.x; wT[(me0 + 1) * MSTR + mc] = wv.y;
        wT[(me0 + 2) * MSTR + mc] = wv.z; wT[(me0 + 3) * MSTR + mc] = wv.w;
        __syncthreads();

#pragma unroll
        for (int e = 0; e < ESTEP; ++e) {
            float a[8], m[4], w[4];
            *(float4*)&a[0] = *(const float4*)&xT[e * XSTR + tm * 8];
            *(float4*)&a[4] = *(const float4*)&xT[e * XSTR + tm * 8 + 4];
            *(float4*)&m[0] = *(const float4*)&mT[e * MSTR + tn * 4];
            *(float4*)&w[0] = *(const float4*)&wT[e * MSTR + tn * 4];
#pragma unroll
            for (int i = 0; i < 8; ++i)
#pragma unroll
                for (int j = 0; j < 4; ++j)
                    acc[i][j] = fmaf(fmaxf(a[i] + m[j], 0.f), w[j], acc[i][j]);
        }
    }

    const bool addb = (blockIdx.z == 0);
#pragma unroll
    for (int j = 0; j < 4; ++j) {
        const int c = c0 + tn * 4 + j;
        if (c >= NCOL) continue;
        const float bv = addb ? (c < NCLS ? p1b[0] : p2b[c - NCLS]) : 0.f;
#pragma unroll
        for (int i = 0; i < 8; ++i) {
            const int gb = b0 + tm * 8 + i;
            if (c < NCLS) atomicAdd(&logits[(size_t)gb * NCLS + c], acc[i][j] + bv);
            else          atomicAdd(&u[(size_t)gb * P_ + (c - NCLS)], acc[i][j] + bv);
        }
    }
}

// ---------------------------------------------------------------------------
// K4: row-normalize u, store sq_n. One wave per row.
// ---------------------------------------------------------------------------
__global__ __launch_bounds__(256) void norm_rows(float* __restrict__ u,
                                                 float* __restrict__ sqn)
{
    const int wave = threadIdx.x >> 6;
    const int lane = threadIdx.x & 63;
    const int row  = blockIdx.x * 4 + wave;
    float v = u[(size_t)row * P_ + lane];
    float s = v * v;
#pragma unroll
    for (int off = 32; off; off >>= 1) s += __shfl_xor(s, off);
    float inv = 1.f / fmaxf(sqrtf(s), 1e-12f);
    u[(size_t)row * P_ + lane] = v * inv;
    if (lane == 0) sqn[row] = s * inv * inv;
}

// ---------------------------------------------------------------------------
// K5: classification loss. One wave per row b.
// ---------------------------------------------------------------------------
__global__ __launch_bounds__(256) void cls_loss(const float* __restrict__ logits,
                                                const int* __restrict__ lb,
                                                float* __restrict__ part)
{
    const int wave = threadIdx.x >> 6;
    const int lane = threadIdx.x & 63;
    const int b    = blockIdx.x * 4 + wave;
    const float* row = logits + (size_t)b * NCLS;
    const int l = lb[b];

    float mx = -1e30f;
    for (int j = lane; j < NCLS; j += 64) {
        bool excl = (j == l) && (l < C_);
        float v = row[j];
        if (!excl) mx = fmaxf(mx, v);
    }
#pragma unroll
    for (int off = 32; off; off >>= 1) mx = fmaxf(mx, __shfl_xor(mx, off));
    float se = 0.f;
    for (int j = lane; j < NCLS; j += 64) {
        bool excl = (j == l) && (l < C_);
        if (!excl) se += expf(row[j] - mx);
    }
#pragma unroll
    for (int off = 32; off; off >>= 1) se += __shfl_xor(se, off);

    if (lane == 0) {
        float l150 = row[C_];
        float loss2 = mx + logf(se) - l150;
        float loss1 = 0.f;
        if (l < C_) {
            float a  = row[l];
            float m2 = fmaxf(a, l150);
            loss1 = m2 - a + logf(expf(a - m2) + expf(l150 - m2));
        }
        atomicAdd(part + 0, loss1 + loss2);
    }
}

// ---------------------------------------------------------------------------
// K6: pairwise margin losses. 32x32 pair tile per block, 2x2 per thread.
// ---------------------------------------------------------------------------
__global__ __launch_bounds__(256) void pair_loss(
    const float* __restrict__ u, const float* __restrict__ sqn,
    const int* __restrict__ lb, float* __restrict__ part)
{
    __shared__ float ui[32][68];
    __shared__ float uj[32][68];
    __shared__ float sni[32], snj[32];
    __shared__ int   li[32],  lj[32];
    __shared__ float red[4][4];

    const int t  = threadIdx.x;
    const int i0 = blockIdx.x * 32, j0 = blockIdx.y * 32;

    for (int idx = t; idx < 512; idx += 256) {
        int r = idx >> 4, e4 = idx & 15;
        ((float4*)&ui[r][0])[e4] = ((const float4*)(u + (size_t)(i0 + r) * P_))[e4];
        ((float4*)&uj[r][0])[e4] = ((const float4*)(u + (size_t)(j0 + r) * P_))[e4];
    }
    if (t < 32) {
        sni[t] = sqn[i0 + t]; li[t] = lb[i0 + t];
        snj[t] = sqn[j0 + t]; lj[t] = lb[j0 + t];
    }
    __syncthreads();

    const int ti = (t & 15) * 2, tj = (t >> 4) * 2;
    float dot[2][2] = {};
#pragma unroll
    for (int k = 0; k < 64; k += 4) {
        float4 a0 = *(const float4*)&ui[ti][k];
        float4 a1 = *(const float4*)&ui[ti + 1][k];
        float4 b0 = *(const float4*)&uj[tj][k];
        float4 b1 = *(const float4*)&uj[tj + 1][k];
        dot[0][0] += a0.x*b0.x + a0.y*b0.y + a0.z*b0.z + a0.w*b0.w;
        dot[0][1] += a0.x*b1.x + a0.y*b1.y + a0.z*b1.z + a0.w*b1.w;
        dot[1][0] += a1.x*b0.x + a1.y*b0.y + a1.z*b0.z + a1.w*b0.w;
        dot[1][1] += a1.x*b1.x + a1.y*b1.y + a1.z*b1.z + a1.w*b1.w;
    }

    float ps = 0.f, pc = 0.f, ns = 0.f, nc = 0.f;
#pragma unroll
    for (int ii = 0; ii < 2; ++ii)
#pragma unroll
        for (int jj = 0; jj < 2; ++jj) {
            int gi = i0 + ti + ii, gj = j0 + tj + jj;
            float sq = sni[ti + ii] + snj[tj + jj] - 2.f * dot[ii][jj];
            float dist = sq > 0.f ? sqrtf(fmaxf(sq, 1e-16f)) : 0.f;
            bool same = (li[ti + ii] == lj[tj + jj]);
            if (same) {
                if (gi != gj) { ps += fmaxf(dist - 0.7f, 0.f); pc += 1.f; }
            } else {
                ns += fmaxf(1.4f - dist, 0.f); nc += 1.f;
            }
        }

#pragma unroll
    for (int off = 32; off; off >>= 1) {
        ps += __shfl_xor(ps, off); pc += __shfl_xor(pc, off);
        ns += __shfl_xor(ns, off); nc += __shfl_xor(nc, off);
    }
    const int wv = t >> 6, ln = t & 63;
    if (ln == 0) { red[0][wv] = ps; red[1][wv] = pc; red[2][wv] = ns; red[3][wv] = nc; }
    __syncthreads();
    if (t == 0) {
        float a = red[0][0] + red[0][1] + red[0][2] + red[0][3];
        float b = red[1][0] + red[1][1] + red[1][2] + red[1][3];
        float c = red[2][0] + red[2][1] + red[2][2] + red[2][3];
        float d = red[3][0] + red[3][1] + red[3][2] + red[3][3];
        atomicAdd(part + 1, a); atomicAdd(part + 2, b);
        atomicAdd(part + 3, c); atomicAdd(part + 4, d);
    }
}

// ---------------------------------------------------------------------------
// K7: finalize scalar loss.
// ---------------------------------------------------------------------------
__global__ void finalize(const float* __restrict__ part, float* __restrict__ out)
{
    if (threadIdx.x == 0 && blockIdx.x == 0) {
        float cls = part[0] / (float)B_;
        float pos = part[1] / fmaxf(part[2], 1.f);
        float neg = part[3] / fmaxf(part[4], 1.f);
        out[0] = cls + pos + neg;
    }
}

extern "C" void kernel_launch(void* const* d_in, const int* in_sizes, int n_in,
                              void* d_out, int out_size, void* d_ws, size_t ws_size,
                              hipStream_t stream)
{
    const float* x    = (const float*)d_in[0];
    const int*   lb   = (const int*)d_in[1];
    const float* mem  = (const float*)d_in[2];
    const float* fc_w = (const float*)d_in[3];
    const float* fc_b = (const float*)d_in[4];
    const float* p1w  = (const float*)d_in[5];
    const float* p1b  = (const float*)d_in[6];
    const float* p2w  = (const float*)d_in[7];
    const float* p2b  = (const float*)d_in[8];

    float* ws     = (float*)d_ws;
    float* mh     = ws + OFF_MH;
    float* xh     = ws + OFF_XH;
    float* logits = ws + OFF_LOGITS;
    float* u      = ws + OFF_U;
    float* sqn    = ws + OFF_SQN;
    float* part   = ws + OFF_PART;
    ushort* xbf   = (ushort*)(ws + OFF_XBF);
    ushort* membf = (ushort*)(ws + OFF_MEMBF);
    ushort* wbf   = (ushort*)(ws + OFF_WBF);

    // zero atomic accumulation targets (logits, u, sqn, part are contiguous)
    hipMemsetAsync(logits, 0,
                   (size_t)(B_ * NCLS + B_ * P_ + B_ + 8) * sizeof(float), stream);

    // K0: fp32 -> bf16
    to_bf16<<<(TOT4 + 255) / 256, 256, 0, stream>>>(x, mem, fc_w,
                                                    xbf, membf, wbf);
    // K1: mh = mem @ Wm^T (Wm = fc_w[:, 768:]), no bias
    gemm_mfma<<<dim3(2, 12), 256, 0, stream>>>(membf, C_, D_, wbf, TWOD, D_,
                                               nullptr, mh, TWOD, D_);
    // K2: xh = x @ Wx^T + fc_b
    gemm_mfma<<<dim3(8, 12), 256, 0, stream>>>(xbf, B_, D_, wbf, TWOD, 0,
                                               fc_b, xh, TWOD, D_);
    // K3: logits (seen + unseen) and raw u projection, e-split with atomics
    fused_tile<<<dim3(8, 4, ECHUNKS), 256, 0, stream>>>(xh, mh, p1w, p1b,
                                                        p2w, p2b, logits, u);
    // K4: normalize u rows
    norm_rows<<<256, 256, 0, stream>>>(u, sqn);
    // K5: classification loss partial sum
    cls_loss<<<256, 256, 0, stream>>>(logits, lb, part);
    // K6: pairwise margin losses
    pair_loss<<<dim3(32, 32), 256, 0, stream>>>(u, sqn, lb, part);
    // K7: write scalar output
    finalize<<<1, 64, 0, stream>>>(part, (float*)d_out);
}

// Round 4
// 261.392 us; speedup vs baseline: 1.4704x; 1.4704x over previous
//
#include <hip/hip_runtime.h>
#include <math.h>

// Problem constants
#define B_    1024
#define D_    768
#define C_    150
#define P_    64
#define TWOD  1536
#define NCLS  151   // C+1
#define NCOL  215   // 151 logits + 64 u-projection cols
#define CPAD  256   // padded column count for partials

// fused_tile config: 128b x 64c per block, 8x4 per thread, e split 16 ways
#define ECHUNKS 16
#define ECHUNK  96    // TWOD / ECHUNKS
#define ESTEP   16

// Workspace layout (float offsets)
#define OFF_MH      0
#define OFF_XH      (OFF_MH + C_ * TWOD)                 // 230400
#define OFF_PARTIAL (OFF_XH + B_ * TWOD)                 // 1803264
#define OFF_U       (OFF_PARTIAL + ECHUNKS * B_ * CPAD)  // +4194304
#define OFF_SQN     (OFF_U + B_ * P_)
#define OFF_PART    (OFF_SQN + B_)
// total ~6.07M floats ~ 24.3 MB

typedef __bf16 bfx8 __attribute__((ext_vector_type(8)));
typedef float  f32x4 __attribute__((ext_vector_type(4)));

__device__ inline ushort f2bf(float f) {
    union { float f; unsigned u; } c; c.f = f;
    unsigned r = c.u + 0x7fffu + ((c.u >> 16) & 1u);
    return (ushort)(r >> 16);
}

// ---------------------------------------------------------------------------
// K1/K2: bf16 MFMA GEMM (NT) with in-register fp32->bf16 staging.
// Out[m,n] = sum_k A[m,k]*Bw[n,koff+k] (+bias[n]). 128x128 tile, BK=32,
// 4 waves (2x2 of 64x64), mfma_f32_16x16x32_bf16. N multiple of 128, M masked.
// ---------------------------------------------------------------------------
__global__ __launch_bounds__(256) void gemm_mfma(
    const float* __restrict__ A, int M, int lda,
    const float* __restrict__ Bw, int ldb, int koff,
    const float* __restrict__ bias,
    float* __restrict__ Out, int ldo, int K)
{
    __shared__ ushort As[128 * 32];
    __shared__ ushort Bs[128 * 32];
    const int t    = threadIdx.x;
    const int m0   = blockIdx.x * 128, n0 = blockIdx.y * 128;
    const int wave = t >> 6, lane = t & 63;
    const int wm   = (wave & 1) * 64, wn = (wave >> 1) * 64;
    const int fm   = lane & 15, quad = lane >> 4;

    f32x4 acc[4][4];
#pragma unroll
    for (int i = 0; i < 4; ++i)
#pragma unroll
        for (int j = 0; j < 4; ++j) acc[i][j] = (f32x4){0.f, 0.f, 0.f, 0.f};

    for (int k0 = 0; k0 < K; k0 += 32) {
        ushort apk[2][8], bpk[2][8];
#pragma unroll
        for (int s = 0; s < 2; ++s) {
            int c = t + s * 256;
            int row = c >> 2, q = c & 3;
            int ar = m0 + row; ar = ar < M ? ar : (M - 1);
            float4 a0 = *(const float4*)&A[(size_t)ar * lda + k0 + q * 8];
            float4 a1 = *(const float4*)&A[(size_t)ar * lda + k0 + q * 8 + 4];
            float4 b0 = *(const float4*)&Bw[(size_t)(n0 + row) * ldb + koff + k0 + q * 8];
            float4 b1 = *(const float4*)&Bw[(size_t)(n0 + row) * ldb + koff + k0 + q * 8 + 4];
            apk[s][0] = f2bf(a0.x); apk[s][1] = f2bf(a0.y);
            apk[s][2] = f2bf(a0.z); apk[s][3] = f2bf(a0.w);
            apk[s][4] = f2bf(a1.x); apk[s][5] = f2bf(a1.y);
            apk[s][6] = f2bf(a1.z); apk[s][7] = f2bf(a1.w);
            bpk[s][0] = f2bf(b0.x); bpk[s][1] = f2bf(b0.y);
            bpk[s][2] = f2bf(b0.z); bpk[s][3] = f2bf(b0.w);
            bpk[s][4] = f2bf(b1.x); bpk[s][5] = f2bf(b1.y);
            bpk[s][6] = f2bf(b1.z); bpk[s][7] = f2bf(b1.w);
        }
        __syncthreads();   // previous step's frag reads complete
#pragma unroll
        for (int s = 0; s < 2; ++s) {
            int c = t + s * 256;
            int row = c >> 2, q = c & 3;
            *(uint4*)&As[row * 32 + q * 8] = *(const uint4*)&apk[s][0];
            *(uint4*)&Bs[row * 32 + q * 8] = *(const uint4*)&bpk[s][0];
        }
        __syncthreads();

        bfx8 af[4], bfr[4];
#pragma unroll
        for (int i = 0; i < 4; ++i) {
            af[i]  = *(const bfx8*)&As[(wm + i * 16 + fm) * 32 + quad * 8];
            bfr[i] = *(const bfx8*)&Bs[(wn + i * 16 + fm) * 32 + quad * 8];
        }
#pragma unroll
        for (int i = 0; i < 4; ++i)
#pragma unroll
            for (int j = 0; j < 4; ++j)
                acc[i][j] = __builtin_amdgcn_mfma_f32_16x16x32_bf16(
                    af[i], bfr[j], acc[i][j], 0, 0, 0);
    }

#pragma unroll
    for (int i = 0; i < 4; ++i)
#pragma unroll
        for (int j = 0; j < 4; ++j)
#pragma unroll
            for (int r = 0; r < 4; ++r) {
                int row = m0 + wm + i * 16 + quad * 4 + r;
                int col = n0 + wn + j * 16 + fm;
                if (row < M)
                    Out[(size_t)row * ldo + col] =
                        acc[i][j][r] + (bias ? bias[col] : 0.f);
            }
}

// ---------------------------------------------------------------------------
// K3: fused tile: partial[z][b][c] = sum_{e in chunk z} relu(xh+m)*w
//   c <150: m=mh[c], w=p1 ; c==150: m=0, w=p1 ; c in [151,215): m=0, w=p2w
// 128b x 64c per block, 8x4 per thread. Plain float4 stores (no atomics).
// LDS staging lane-minor: writes are 2-way bank-aliased = free (m136).
// ---------------------------------------------------------------------------
__global__ __launch_bounds__(256) void fused_tile(
    const float* __restrict__ xh, const float* __restrict__ mh,
    const float* __restrict__ p1w, const float* __restrict__ p2w,
    float* __restrict__ partial)
{
    __shared__ float xT[ESTEP * 128];   // [e][b] 8 KB
    __shared__ float mT[ESTEP * 64];    // [e][c] 4 KB
    __shared__ float wT[ESTEP * 64];    // [e][c] 4 KB

    const int t  = threadIdx.x;
    const int b0 = blockIdx.x * 128;
    const int c0 = blockIdx.y * 64;
    const int z  = blockIdx.z;
    const int e0 = z * ECHUNK;
    const int tm = t & 15;      // 8 b-rows each
    const int tn = t >> 4;      // 4 c-cols each

    // staging roles (lane-minor rows -> conflict-free LDS writes)
    const int xr  = t & 127, xs8 = (t >> 7) * 8;       // x: 2 thr/row, 8 e
    const int mc  = t & 63,  ms4 = ((t >> 6) & 3) * 4; // m/w: 4 thr/col, 4 e
    const int gc  = c0 + mc;
    const bool cseen = gc < C_;
    const bool cu    = (gc >= NCLS) && (gc < NCOL);
    const bool wok   = gc < NCOL;
    const float* xrow = xh + (size_t)(b0 + xr) * TWOD;
    const float* mrow = mh + (size_t)(cseen ? gc : 0) * TWOD;
    const float* wrow = cu ? (p2w + (size_t)(gc - NCLS) * TWOD) : p1w;

    float acc[8][4] = {};

    for (int es = 0; es < ECHUNK; es += ESTEP) {
        const int eb = e0 + es;
        float4 x0 = *(const float4*)&xrow[eb + xs8];
        float4 x1 = *(const float4*)&xrow[eb + xs8 + 4];
        float4 mv = cseen ? *(const float4*)&mrow[eb + ms4]
                          : make_float4(0.f, 0.f, 0.f, 0.f);
        float4 wv = wok   ? *(const float4*)&wrow[eb + ms4]
                          : make_float4(0.f, 0.f, 0.f, 0.f);
        __syncthreads();   // previous step's LDS reads complete
        xT[(xs8 + 0) * 128 + xr] = x0.x; xT[(xs8 + 1) * 128 + xr] = x0.y;
        xT[(xs8 + 2) * 128 + xr] = x0.z; xT[(xs8 + 3) * 128 + xr] = x0.w;
        xT[(xs8 + 4) * 128 + xr] = x1.x; xT[(xs8 + 5) * 128 + xr] = x1.y;
        xT[(xs8 + 6) * 128 + xr] = x1.z; xT[(xs8 + 7) * 128 + xr] = x1.w;
        mT[(ms4 + 0) * 64 + mc] = mv.x; mT[(ms4 + 1) * 64 + mc] = mv.y;
        mT[(ms4 + 2) * 64 + mc] = mv.z; mT[(ms4 + 3) * 64 + mc] = mv.w;
        wT[(ms4 + 0) * 64 + mc] = wv.x; wT[(ms4 + 1) * 64 + mc] = wv.y;
        wT[(ms4 + 2) * 64 + mc] = wv.z; wT[(ms4 + 3) * 64 + mc] = wv.w;
        __syncthreads();

#pragma unroll 4
        for (int e = 0; e < ESTEP; ++e) {
            float a[8], m[4], w[4];
            *(float4*)&a[0] = *(const float4*)&xT[e * 128 + tm * 8];
            *(float4*)&a[4] = *(const float4*)&xT[e * 128 + tm * 8 + 4];
            *(float4*)&m[0] = *(const float4*)&mT[e * 64 + tn * 4];
            *(float4*)&w[0] = *(const float4*)&wT[e * 64 + tn * 4];
#pragma unroll
            for (int i = 0; i < 8; ++i)
#pragma unroll
                for (int j = 0; j < 4; ++j)
                    acc[i][j] = fmaf(fmaxf(a[i] + m[j], 0.f), w[j], acc[i][j]);
        }
    }

#pragma unroll
    for (int i = 0; i < 8; ++i) {
        const int gb = b0 + tm * 8 + i;
        float4 v = make_float4(acc[i][0], acc[i][1], acc[i][2], acc[i][3]);
        *(float4*)&partial[((size_t)z * B_ + gb) * CPAD + c0 + tn * 4] = v;
    }
}

// ---------------------------------------------------------------------------
// K4: per-row reduce of partials + bias, then u-normalize + cls loss.
// One block per b-row; thread t owns column t. Logits never hit HBM.
// ---------------------------------------------------------------------------
__global__ __launch_bounds__(256) void reduce_row(
    const float* __restrict__ partial,
    const float* __restrict__ p1b, const float* __restrict__ p2b,
    const int* __restrict__ lb,
    float* __restrict__ u, float* __restrict__ sqn, float* __restrict__ part)
{
    const int b = blockIdx.x, t = threadIdx.x;
    float v = 0.f;
#pragma unroll
    for (int z = 0; z < ECHUNKS; ++z)
        v += partial[((size_t)z * B_ + b) * CPAD + t];
    if (t < NCLS)      v += p1b[0];
    else if (t < NCOL) v += p2b[t - NCLS];

    __shared__ float sval[256];
    sval[t] = v;
    __syncthreads();

    if (t < 64) {
        // ---- u normalization (cols 151..214) ----
        float uv = sval[NCLS + t];
        float s = uv * uv;
#pragma unroll
        for (int off = 32; off; off >>= 1) s += __shfl_xor(s, off);
        float inv = 1.f / fmaxf(sqrtf(s), 1e-12f);
        u[(size_t)b * P_ + t] = uv * inv;
        if (t == 0) sqn[b] = s * inv * inv;

        // ---- classification loss over cols 0..150 ----
        const int l = lb[b];
        float mx = -1e30f;
        for (int j = t; j < NCLS; j += 64)
            if (!(j == l && l < C_)) mx = fmaxf(mx, sval[j]);
#pragma unroll
        for (int off = 32; off; off >>= 1) mx = fmaxf(mx, __shfl_xor(mx, off));
        float se = 0.f;
        for (int j = t; j < NCLS; j += 64)
            if (!(j == l && l < C_)) se += expf(sval[j] - mx);
#pragma unroll
        for (int off = 32; off; off >>= 1) se += __shfl_xor(se, off);

        if (t == 0) {
            float l150  = sval[C_];
            float loss2 = mx + logf(se) - l150;
            float loss1 = 0.f;
            if (l < C_) {
                float a  = sval[l];
                float m2 = fmaxf(a, l150);
                loss1 = m2 - a + logf(expf(a - m2) + expf(l150 - m2));
            }
            atomicAdd(part + 0, loss1 + loss2);
        }
    }
}

// ---------------------------------------------------------------------------
// K5: pairwise margin losses. 32x32 pair tile per block, 2x2 per thread.
// ---------------------------------------------------------------------------
__global__ __launch_bounds__(256) void pair_loss(
    const float* __restrict__ u, const float* __restrict__ sqn,
    const int* __restrict__ lb, float* __restrict__ part)
{
    __shared__ float ui[32][68];
    __shared__ float uj[32][68];
    __shared__ float sni[32], snj[32];
    __shared__ int   li[32],  lj[32];
    __shared__ float red[4][4];

    const int t  = threadIdx.x;
    const int i0 = blockIdx.x * 32, j0 = blockIdx.y * 32;

    for (int idx = t; idx < 512; idx += 256) {
        int r = idx >> 4, e4 = idx & 15;
        ((float4*)&ui[r][0])[e4] = ((const float4*)(u + (size_t)(i0 + r) * P_))[e4];
        ((float4*)&uj[r][0])[e4] = ((const float4*)(u + (size_t)(j0 + r) * P_))[e4];
    }
    if (t < 32) {
        sni[t] = sqn[i0 + t]; li[t] = lb[i0 + t];
        snj[t] = sqn[j0 + t]; lj[t] = lb[j0 + t];
    }
    __syncthreads();

    const int ti = (t & 15) * 2, tj = (t >> 4) * 2;
    float dot[2][2] = {};
#pragma unroll
    for (int k = 0; k < 64; k += 4) {
        float4 a0 = *(const float4*)&ui[ti][k];
        float4 a1 = *(const float4*)&ui[ti + 1][k];
        float4 b0 = *(const float4*)&uj[tj][k];
        float4 b1 = *(const float4*)&uj[tj + 1][k];
        dot[0][0] += a0.x*b0.x + a0.y*b0.y + a0.z*b0.z + a0.w*b0.w;
        dot[0][1] += a0.x*b1.x + a0.y*b1.y + a0.z*b1.z + a0.w*b1.w;
        dot[1][0] += a1.x*b0.x + a1.y*b0.y + a1.z*b0.z + a1.w*b0.w;
        dot[1][1] += a1.x*b1.x + a1.y*b1.y + a1.z*b1.z + a1.w*b1.w;
    }

    float ps = 0.f, pc = 0.f, ns = 0.f, nc = 0.f;
#pragma unroll
    for (int ii = 0; ii < 2; ++ii)
#pragma unroll
        for (int jj = 0; jj < 2; ++jj) {
            int gi = i0 + ti + ii, gj = j0 + tj + jj;
            float sq = sni[ti + ii] + snj[tj + jj] - 2.f * dot[ii][jj];
            float dist = sq > 0.f ? sqrtf(fmaxf(sq, 1e-16f)) : 0.f;
            bool same = (li[ti + ii] == lj[tj + jj]);
            if (same) {
                if (gi != gj) { ps += fmaxf(dist - 0.7f, 0.f); pc += 1.f; }
            } else {
                ns += fmaxf(1.4f - dist, 0.f); nc += 1.f;
            }
        }

#pragma unroll
    for (int off = 32; off; off >>= 1) {
        ps += __shfl_xor(ps, off); pc += __shfl_xor(pc, off);
        ns += __shfl_xor(ns, off); nc += __shfl_xor(nc, off);
    }
    const int wv = t >> 6, ln = t & 63;
    if (ln == 0) { red[0][wv] = ps; red[1][wv] = pc; red[2][wv] = ns; red[3][wv] = nc; }
    __syncthreads();
    if (t == 0) {
        float a = red[0][0] + red[0][1] + red[0][2] + red[0][3];
        float b = red[1][0] + red[1][1] + red[1][2] + red[1][3];
        float c = red[2][0] + red[2][1] + red[2][2] + red[2][3];
        float d = red[3][0] + red[3][1] + red[3][2] + red[3][3];
        atomicAdd(part + 1, a); atomicAdd(part + 2, b);
        atomicAdd(part + 3, c); atomicAdd(part + 4, d);
    }
}

// ---------------------------------------------------------------------------
// K6: finalize scalar loss.
// ---------------------------------------------------------------------------
__global__ void finalize(const float* __restrict__ part, float* __restrict__ out)
{
    if (threadIdx.x == 0 && blockIdx.x == 0) {
        float cls = part[0] / (float)B_;
        float pos = part[1] / fmaxf(part[2], 1.f);
        float neg = part[3] / fmaxf(part[4], 1.f);
        out[0] = cls + pos + neg;
    }
}

extern "C" void kernel_launch(void* const* d_in, const int* in_sizes, int n_in,
                              void* d_out, int out_size, void* d_ws, size_t ws_size,
                              hipStream_t stream)
{
    const float* x    = (const float*)d_in[0];
    const int*   lb   = (const int*)d_in[1];
    const float* mem  = (const float*)d_in[2];
    const float* fc_w = (const float*)d_in[3];
    const float* fc_b = (const float*)d_in[4];
    const float* p1w  = (const float*)d_in[5];
    const float* p1b  = (const float*)d_in[6];
    const float* p2w  = (const float*)d_in[7];
    const float* p2b  = (const float*)d_in[8];

    float* ws      = (float*)d_ws;
    float* mh      = ws + OFF_MH;
    float* xh      = ws + OFF_XH;
    float* partials= ws + OFF_PARTIAL;
    float* u       = ws + OFF_U;
    float* sqn     = ws + OFF_SQN;
    float* part    = ws + OFF_PART;

    hipMemsetAsync(part, 0, 8 * sizeof(float), stream);

    // K1: mh = mem @ Wm^T (Wm = fc_w[:, 768:]), no bias
    gemm_mfma<<<dim3(2, 12), 256, 0, stream>>>(mem, C_, D_, fc_w, TWOD, D_,
                                               nullptr, mh, TWOD, D_);
    // K2: xh = x @ Wx^T + fc_b
    gemm_mfma<<<dim3(8, 12), 256, 0, stream>>>(x, B_, D_, fc_w, TWOD, 0,
                                               fc_b, xh, TWOD, D_);
    // K3: e-split partials of logits (0..150) and raw u-projection (151..214)
    fused_tile<<<dim3(8, 4, ECHUNKS), 256, 0, stream>>>(xh, mh, p1w, p2w,
                                                        partials);
    // K4: reduce partials + bias, normalize u, classification loss
    reduce_row<<<B_, 256, 0, stream>>>(partials, p1b, p2b, lb, u, sqn, part);
    // K5: pairwise margin losses
    pair_loss<<<dim3(32, 32), 256, 0, stream>>>(u, sqn, lb, part);
    // K6: write scalar output
    finalize<<<1, 64, 0, stream>>>(part, (float*)d_out);
}

// Round 5
// 196.119 us; speedup vs baseline: 1.9598x; 1.3328x over previous
//
#include <hip/hip_runtime.h>
#include <math.h>

// Problem constants
#define B_    1024
#define D_    768
#define C_    150
#define P_    64
#define TWOD  1536
#define NCLS  151   // C+1
#define NCOL  215   // 151 logits + 64 u-projection cols
#define CPAD  256   // padded column count for partials

// fused_tile config: 128b x 64c per block, 8x4 per thread, e split 16 ways
#define ECHUNKS 16
#define ECHUNK  96    // TWOD / ECHUNKS
#define ESTEP   16

// pair_loss config
#define USTR  72      // LDS row stride (ushorts); 144 B = 16B-aligned rows

// Workspace layout (float offsets)
#define OFF_MH      0
#define OFF_XH      (OFF_MH + C_ * TWOD)                 // 230400
#define OFF_PARTIAL (OFF_XH + B_ * TWOD)                 // 1803264
#define OFF_UBF     (OFF_PARTIAL + ECHUNKS * B_ * CPAD)  // ushort[1024*64] = 32768 floats
#define OFF_SQN     (OFF_UBF + (B_ * P_) / 2)
#define OFF_CLS     (OFF_SQN + B_)
#define OFF_PAIR    (OFF_CLS + B_)                       // 256 blocks * 4 floats
// total ~6.03M floats ~ 24.1 MB

typedef __bf16 bfx8 __attribute__((ext_vector_type(8)));
typedef float  f32x4 __attribute__((ext_vector_type(4)));

__device__ inline ushort f2bf(float f) {
    union { float f; unsigned u; } c; c.f = f;
    unsigned r = c.u + 0x7fffu + ((c.u >> 16) & 1u);
    return (ushort)(r >> 16);
}

// ---------------------------------------------------------------------------
// K1/K2: bf16 MFMA GEMM (NT) with in-register fp32->bf16 staging.
// Out[m,n] = sum_k A[m,k]*Bw[n,koff+k] (+bias[n]). 128x128 tile, BK=32,
// 4 waves (2x2 of 64x64), mfma_f32_16x16x32_bf16. N multiple of 128, M masked.
// ---------------------------------------------------------------------------
__global__ __launch_bounds__(256) void gemm_mfma(
    const float* __restrict__ A, int M, int lda,
    const float* __restrict__ Bw, int ldb, int koff,
    const float* __restrict__ bias,
    float* __restrict__ Out, int ldo, int K)
{
    __shared__ ushort As[128 * 32];
    __shared__ ushort Bs[128 * 32];
    const int t    = threadIdx.x;
    const int m0   = blockIdx.x * 128, n0 = blockIdx.y * 128;
    const int wave = t >> 6, lane = t & 63;
    const int wm   = (wave & 1) * 64, wn = (wave >> 1) * 64;
    const int fm   = lane & 15, quad = lane >> 4;

    f32x4 acc[4][4];
#pragma unroll
    for (int i = 0; i < 4; ++i)
#pragma unroll
        for (int j = 0; j < 4; ++j) acc[i][j] = (f32x4){0.f, 0.f, 0.f, 0.f};

    for (int k0 = 0; k0 < K; k0 += 32) {
        ushort apk[2][8], bpk[2][8];
#pragma unroll
        for (int s = 0; s < 2; ++s) {
            int c = t + s * 256;
            int row = c >> 2, q = c & 3;
            int ar = m0 + row; ar = ar < M ? ar : (M - 1);
            float4 a0 = *(const float4*)&A[(size_t)ar * lda + k0 + q * 8];
            float4 a1 = *(const float4*)&A[(size_t)ar * lda + k0 + q * 8 + 4];
            float4 b0 = *(const float4*)&Bw[(size_t)(n0 + row) * ldb + koff + k0 + q * 8];
            float4 b1 = *(const float4*)&Bw[(size_t)(n0 + row) * ldb + koff + k0 + q * 8 + 4];
            apk[s][0] = f2bf(a0.x); apk[s][1] = f2bf(a0.y);
            apk[s][2] = f2bf(a0.z); apk[s][3] = f2bf(a0.w);
            apk[s][4] = f2bf(a1.x); apk[s][5] = f2bf(a1.y);
            apk[s][6] = f2bf(a1.z); apk[s][7] = f2bf(a1.w);
            bpk[s][0] = f2bf(b0.x); bpk[s][1] = f2bf(b0.y);
            bpk[s][2] = f2bf(b0.z); bpk[s][3] = f2bf(b0.w);
            bpk[s][4] = f2bf(b1.x); bpk[s][5] = f2bf(b1.y);
            bpk[s][6] = f2bf(b1.z); bpk[s][7] = f2bf(b1.w);
        }
        __syncthreads();   // previous step's frag reads complete
#pragma unroll
        for (int s = 0; s < 2; ++s) {
            int c = t + s * 256;
            int row = c >> 2, q = c & 3;
            *(uint4*)&As[row * 32 + q * 8] = *(const uint4*)&apk[s][0];
            *(uint4*)&Bs[row * 32 + q * 8] = *(const uint4*)&bpk[s][0];
        }
        __syncthreads();

        bfx8 af[4], bfr[4];
#pragma unroll
        for (int i = 0; i < 4; ++i) {
            af[i]  = *(const bfx8*)&As[(wm + i * 16 + fm) * 32 + quad * 8];
            bfr[i] = *(const bfx8*)&Bs[(wn + i * 16 + fm) * 32 + quad * 8];
        }
#pragma unroll
        for (int i = 0; i < 4; ++i)
#pragma unroll
            for (int j = 0; j < 4; ++j)
                acc[i][j] = __builtin_amdgcn_mfma_f32_16x16x32_bf16(
                    af[i], bfr[j], acc[i][j], 0, 0, 0);
    }

#pragma unroll
    for (int i = 0; i < 4; ++i)
#pragma unroll
        for (int j = 0; j < 4; ++j)
#pragma unroll
            for (int r = 0; r < 4; ++r) {
                int row = m0 + wm + i * 16 + quad * 4 + r;
                int col = n0 + wn + j * 16 + fm;
                if (row < M)
                    Out[(size_t)row * ldo + col] =
                        acc[i][j][r] + (bias ? bias[col] : 0.f);
            }
}

// ---------------------------------------------------------------------------
// K3: fused tile: partial[z][b][c] = sum_{e in chunk z} relu(xh+m)*w
//   c <150: m=mh[c], w=p1 ; c==150: m=0, w=p1 ; c in [151,215): m=0, w=p2w
// 128b x 64c per block, 8x4 per thread. Plain float4 stores (no atomics).
// ---------------------------------------------------------------------------
__global__ __launch_bounds__(256) void fused_tile(
    const float* __restrict__ xh, const float* __restrict__ mh,
    const float* __restrict__ p1w, const float* __restrict__ p2w,
    float* __restrict__ partial)
{
    __shared__ float xT[ESTEP * 128];   // [e][b] 8 KB
    __shared__ float mT[ESTEP * 64];    // [e][c] 4 KB
    __shared__ float wT[ESTEP * 64];    // [e][c] 4 KB

    const int t  = threadIdx.x;
    const int b0 = blockIdx.x * 128;
    const int c0 = blockIdx.y * 64;
    const int z  = blockIdx.z;
    const int e0 = z * ECHUNK;
    const int tm = t & 15;      // 8 b-rows each
    const int tn = t >> 4;      // 4 c-cols each

    const int xr  = t & 127, xs8 = (t >> 7) * 8;       // x: 2 thr/row, 8 e
    const int mc  = t & 63,  ms4 = ((t >> 6) & 3) * 4; // m/w: 4 thr/col, 4 e
    const int gc  = c0 + mc;
    const bool cseen = gc < C_;
    const bool cu    = (gc >= NCLS) && (gc < NCOL);
    const bool wok   = gc < NCOL;
    const float* xrow = xh + (size_t)(b0 + xr) * TWOD;
    const float* mrow = mh + (size_t)(cseen ? gc : 0) * TWOD;
    const float* wrow = cu ? (p2w + (size_t)(gc - NCLS) * TWOD) : p1w;

    float acc[8][4] = {};

    for (int es = 0; es < ECHUNK; es += ESTEP) {
        const int eb = e0 + es;
        float4 x0 = *(const float4*)&xrow[eb + xs8];
        float4 x1 = *(const float4*)&xrow[eb + xs8 + 4];
        float4 mv = cseen ? *(const float4*)&mrow[eb + ms4]
                          : make_float4(0.f, 0.f, 0.f, 0.f);
        float4 wv = wok   ? *(const float4*)&wrow[eb + ms4]
                          : make_float4(0.f, 0.f, 0.f, 0.f);
        __syncthreads();   // previous step's LDS reads complete
        xT[(xs8 + 0) * 128 + xr] = x0.x; xT[(xs8 + 1) * 128 + xr] = x0.y;
        xT[(xs8 + 2) * 128 + xr] = x0.z; xT[(xs8 + 3) * 128 + xr] = x0.w;
        xT[(xs8 + 4) * 128 + xr] = x1.x; xT[(xs8 + 5) * 128 + xr] = x1.y;
        xT[(xs8 + 6) * 128 + xr] = x1.z; xT[(xs8 + 7) * 128 + xr] = x1.w;
        mT[(ms4 + 0) * 64 + mc] = mv.x; mT[(ms4 + 1) * 64 + mc] = mv.y;
        mT[(ms4 + 2) * 64 + mc] = mv.z; mT[(ms4 + 3) * 64 + mc] = mv.w;
        wT[(ms4 + 0) * 64 + mc] = wv.x; wT[(ms4 + 1) * 64 + mc] = wv.y;
        wT[(ms4 + 2) * 64 + mc] = wv.z; wT[(ms4 + 3) * 64 + mc] = wv.w;
        __syncthreads();

#pragma unroll 4
        for (int e = 0; e < ESTEP; ++e) {
            float a[8], m[4], w[4];
            *(float4*)&a[0] = *(const float4*)&xT[e * 128 + tm * 8];
            *(float4*)&a[4] = *(const float4*)&xT[e * 128 + tm * 8 + 4];
            *(float4*)&m[0] = *(const float4*)&mT[e * 64 + tn * 4];
            *(float4*)&w[0] = *(const float4*)&wT[e * 64 + tn * 4];
#pragma unroll
            for (int i = 0; i < 8; ++i)
#pragma unroll
                for (int j = 0; j < 4; ++j)
                    acc[i][j] = fmaf(fmaxf(a[i] + m[j], 0.f), w[j], acc[i][j]);
        }
    }

#pragma unroll
    for (int i = 0; i < 8; ++i) {
        const int gb = b0 + tm * 8 + i;
        float4 v = make_float4(acc[i][0], acc[i][1], acc[i][2], acc[i][3]);
        *(float4*)&partial[((size_t)z * B_ + gb) * CPAD + c0 + tn * 4] = v;
    }
}

// ---------------------------------------------------------------------------
// K4: per-row reduce of partials + bias, u-normalize (-> bf16) + cls loss.
// One block per b-row. No atomics: clsbuf[b] plain store.
// ---------------------------------------------------------------------------
__global__ __launch_bounds__(256) void reduce_row(
    const float* __restrict__ partial,
    const float* __restrict__ p1b, const float* __restrict__ p2b,
    const int* __restrict__ lb,
    ushort* __restrict__ ubf, float* __restrict__ sqn,
    float* __restrict__ clsbuf)
{
    const int b = blockIdx.x, t = threadIdx.x;
    float v = 0.f;
#pragma unroll
    for (int z = 0; z < ECHUNKS; ++z)
        v += partial[((size_t)z * B_ + b) * CPAD + t];
    if (t < NCLS)      v += p1b[0];
    else if (t < NCOL) v += p2b[t - NCLS];

    __shared__ float sval[256];
    sval[t] = v;
    __syncthreads();

    if (t < 64) {
        // ---- u normalization (cols 151..214), store bf16 ----
        float uv = sval[NCLS + t];
        float s = uv * uv;
#pragma unroll
        for (int off = 32; off; off >>= 1) s += __shfl_xor(s, off);
        float inv = 1.f / fmaxf(sqrtf(s), 1e-12f);
        ubf[(size_t)b * P_ + t] = f2bf(uv * inv);
        if (t == 0) sqn[b] = s * inv * inv;

        // ---- classification loss over cols 0..150 ----
        const int l = lb[b];
        float mx = -1e30f;
        for (int j = t; j < NCLS; j += 64)
            if (!(j == l && l < C_)) mx = fmaxf(mx, sval[j]);
#pragma unroll
        for (int off = 32; off; off >>= 1) mx = fmaxf(mx, __shfl_xor(mx, off));
        float se = 0.f;
        for (int j = t; j < NCLS; j += 64)
            if (!(j == l && l < C_)) se += expf(sval[j] - mx);
#pragma unroll
        for (int off = 32; off; off >>= 1) se += __shfl_xor(se, off);

        if (t == 0) {
            float l150  = sval[C_];
            float loss2 = mx + logf(se) - l150;
            float loss1 = 0.f;
            if (l < C_) {
                float a  = sval[l];
                float m2 = fmaxf(a, l150);
                loss1 = m2 - a + logf(expf(a - m2) + expf(l150 - m2));
            }
            clsbuf[b] = loss1 + loss2;
        }
    }
}

// ---------------------------------------------------------------------------
// K5: pairwise margin losses via MFMA Gram tiles. 64x64 pairs per block.
// Per-block partials plain-stored (no atomics). Grid 16x16.
// ---------------------------------------------------------------------------
__global__ __launch_bounds__(256) void pair_loss(
    const ushort* __restrict__ ubf, const float* __restrict__ sqn,
    const int* __restrict__ lb, float* __restrict__ pairpart)
{
    __shared__ ushort ui_s[64 * USTR];
    __shared__ ushort uj_s[64 * USTR];
    __shared__ float sni[64], snj[64];
    __shared__ int   li[64],  lj[64];
    __shared__ float red[4][4];

    const int t  = threadIdx.x;
    const int i0 = blockIdx.x * 64, j0 = blockIdx.y * 64;

    for (int idx = t; idx < 512; idx += 256) {
        int row = idx >> 3, ch = (idx & 7) * 8;
        *(uint4*)&ui_s[row * USTR + ch] =
            *(const uint4*)&ubf[(size_t)(i0 + row) * P_ + ch];
        *(uint4*)&uj_s[row * USTR + ch] =
            *(const uint4*)&ubf[(size_t)(j0 + row) * P_ + ch];
    }
    if (t < 64)       { sni[t] = sqn[i0 + t]; li[t] = lb[i0 + t]; }
    else if (t < 128) { int q = t - 64; snj[q] = sqn[j0 + q]; lj[q] = lb[j0 + q]; }
    __syncthreads();

    const int wave = t >> 6, lane = t & 63;
    const int n = lane & 15, quad = lane >> 4;
    const int iw = wave * 16;

    // A-frag: rows iw..iw+15 of ui (operand orientation as in gemm_mfma)
    const bfx8 af0 = *(const bfx8*)&ui_s[(iw + n) * USTR + quad * 8];
    const bfx8 af1 = *(const bfx8*)&ui_s[(iw + n) * USTR + quad * 8 + 32];

    f32x4 acc[4];
#pragma unroll
    for (int jt = 0; jt < 4; ++jt) {
        const bfx8 bf0 = *(const bfx8*)&uj_s[(jt * 16 + n) * USTR + quad * 8];
        const bfx8 bf1 = *(const bfx8*)&uj_s[(jt * 16 + n) * USTR + quad * 8 + 32];
        acc[jt] = __builtin_amdgcn_mfma_f32_16x16x32_bf16(
            af0, bf0, (f32x4){0.f, 0.f, 0.f, 0.f}, 0, 0, 0);
        acc[jt] = __builtin_amdgcn_mfma_f32_16x16x32_bf16(
            af1, bf1, acc[jt], 0, 0, 0);
    }

    float ps = 0.f, pc = 0.f, ns = 0.f, nc = 0.f;
#pragma unroll
    for (int jt = 0; jt < 4; ++jt)
#pragma unroll
        for (int r = 0; r < 4; ++r) {
            const int il = iw + quad * 4 + r;    // C/D: row = quad*4+reg
            const int jl = jt * 16 + n;          // C/D: col = lane&15
            float sq = sni[il] + snj[jl] - 2.f * acc[jt][r];
            float dist = sq > 0.f ? sqrtf(fmaxf(sq, 1e-16f)) : 0.f;
            bool same = (li[il] == lj[jl]);
            if (same) {
                if (i0 + il != j0 + jl) { ps += fmaxf(dist - 0.7f, 0.f); pc += 1.f; }
            } else {
                ns += fmaxf(1.4f - dist, 0.f); nc += 1.f;
            }
        }

#pragma unroll
    for (int off = 32; off; off >>= 1) {
        ps += __shfl_xor(ps, off); pc += __shfl_xor(pc, off);
        ns += __shfl_xor(ns, off); nc += __shfl_xor(nc, off);
    }
    if (lane == 0) { red[0][wave] = ps; red[1][wave] = pc;
                     red[2][wave] = ns; red[3][wave] = nc; }
    __syncthreads();
    if (t == 0) {
        float4 v;
        v.x = red[0][0] + red[0][1] + red[0][2] + red[0][3];
        v.y = red[1][0] + red[1][1] + red[1][2] + red[1][3];
        v.z = red[2][0] + red[2][1] + red[2][2] + red[2][3];
        v.w = red[3][0] + red[3][1] + red[3][2] + red[3][3];
        *(float4*)&pairpart[(size_t)(blockIdx.y * 16 + blockIdx.x) * 4] = v;
    }
}

// ---------------------------------------------------------------------------
// K6: finalize — reduce clsbuf[1024] and pairpart[256][4], write scalar loss.
// ---------------------------------------------------------------------------
__global__ __launch_bounds__(256) void finalize(
    const float* __restrict__ clsbuf, const float* __restrict__ pairpart,
    float* __restrict__ out)
{
    __shared__ float red[5][4];
    const int t = threadIdx.x;
    float c = clsbuf[t] + clsbuf[t + 256] + clsbuf[t + 512] + clsbuf[t + 768];
    float4 pp = *(const float4*)&pairpart[(size_t)t * 4];
    float ps = pp.x, pc = pp.y, ns = pp.z, nc = pp.w;
#pragma unroll
    for (int off = 32; off; off >>= 1) {
        c  += __shfl_xor(c, off);
        ps += __shfl_xor(ps, off); pc += __shfl_xor(pc, off);
        ns += __shfl_xor(ns, off); nc += __shfl_xor(nc, off);
    }
    const int wave = t >> 6, lane = t & 63;
    if (lane == 0) { red[0][wave] = c; red[1][wave] = ps; red[2][wave] = pc;
                     red[3][wave] = ns; red[4][wave] = nc; }
    __syncthreads();
    if (t == 0) {
        float C = 0.f, PS = 0.f, PC = 0.f, NS = 0.f, NC = 0.f;
#pragma unroll
        for (int w = 0; w < 4; ++w) {
            C += red[0][w]; PS += red[1][w]; PC += red[2][w];
            NS += red[3][w]; NC += red[4][w];
        }
        out[0] = C / (float)B_ + PS / fmaxf(PC, 1.f) + NS / fmaxf(NC, 1.f);
    }
}

extern "C" void kernel_launch(void* const* d_in, const int* in_sizes, int n_in,
                              void* d_out, int out_size, void* d_ws, size_t ws_size,
                              hipStream_t stream)
{
    const float* x    = (const float*)d_in[0];
    const int*   lb   = (const int*)d_in[1];
    const float* mem  = (const float*)d_in[2];
    const float* fc_w = (const float*)d_in[3];
    const float* fc_b = (const float*)d_in[4];
    const float* p1w  = (const float*)d_in[5];
    const float* p1b  = (const float*)d_in[6];
    const float* p2w  = (const float*)d_in[7];
    const float* p2b  = (const float*)d_in[8];

    float* ws       = (float*)d_ws;
    float* mh       = ws + OFF_MH;
    float* xh       = ws + OFF_XH;
    float* partials = ws + OFF_PARTIAL;
    ushort* ubf     = (ushort*)(ws + OFF_UBF);
    float* sqn      = ws + OFF_SQN;
    float* clsbuf   = ws + OFF_CLS;
    float* pairpart = ws + OFF_PAIR;

    // K1: mh = mem @ Wm^T (Wm = fc_w[:, 768:]), no bias
    gemm_mfma<<<dim3(2, 12), 256, 0, stream>>>(mem, C_, D_, fc_w, TWOD, D_,
                                               nullptr, mh, TWOD, D_);
    // K2: xh = x @ Wx^T + fc_b
    gemm_mfma<<<dim3(8, 12), 256, 0, stream>>>(x, B_, D_, fc_w, TWOD, 0,
                                               fc_b, xh, TWOD, D_);
    // K3: e-split partials of logits (0..150) and raw u-projection (151..214)
    fused_tile<<<dim3(8, 4, ECHUNKS), 256, 0, stream>>>(xh, mh, p1w, p2w,
                                                        partials);
    // K4: reduce partials + bias, normalize u (bf16 out), classification loss
    reduce_row<<<B_, 256, 0, stream>>>(partials, p1b, p2b, lb, ubf, sqn, clsbuf);
    // K5: pairwise margin losses (MFMA Gram tiles, no atomics)
    pair_loss<<<dim3(16, 16), 256, 0, stream>>>(ubf, sqn, lb, pairpart);
    // K6: final reduce + write scalar output
    finalize<<<1, 256, 0, stream>>>(clsbuf, pairpart, (float*)d_out);
}

// Round 6
// 143.918 us; speedup vs baseline: 2.6707x; 1.3627x over previous
//
#include <hip/hip_runtime.h>
#include <math.h>

// Problem constants
#define B_    1024
#define D_    768
#define C_    150
#define P_    64
#define TWOD  1536
#define NCLS  151   // C+1
#define CPAD  256   // partial row: cols 0..150 logits, 151..191 junk, 192..255 u

// fused_tile elementwise config: 128b x 64c per block, 8x4/thr, z-split 16
#define ECHUNKS 16
#define ECHUNK  96
#define ESTEP   32

// gemm_all: 64x128 tile, BK=32, bf16 LDS stride 40 (2-way banks)
#define ASTR  40
// u-path LDS stride (ushorts): 120 -> 240B rows, 16B aligned, 2-way banks
#define USTRU 120

// pair_loss LDS stride
#define USTR  72

// Workspace layout (float offsets)
#define OFF_MH      0
#define OFF_XH      (OFF_MH + C_ * TWOD)                  // 230400
#define OFF_PARTIAL (OFF_XH + B_ * TWOD)                  // 1803264
#define OFF_UBF     (OFF_PARTIAL + ECHUNKS * B_ * CPAD)
#define OFF_SQN     (OFF_UBF + (B_ * P_) / 2)
#define OFF_CLS     (OFF_SQN + B_)
#define OFF_PAIR    (OFF_CLS + B_)
#define OFF_XBF     (OFF_PAIR + 1024)
#define OFF_MEMBF   (OFF_XBF + (B_ * D_) / 2)
#define OFF_WBF     (OFF_MEMBF + (C_ * D_) / 2)
#define OFF_P2BF    (OFF_WBF + (TWOD * TWOD) / 2)
// end ~7.72M floats ~ 30.9 MB

typedef __bf16 bfx8 __attribute__((ext_vector_type(8)));
typedef float  f32x4 __attribute__((ext_vector_type(4)));

__device__ inline ushort f2bf(float f) {
    union { float f; unsigned u; } c; c.f = f;
    unsigned r = c.u + 0x7fffu + ((c.u >> 16) & 1u);
    return (ushort)(r >> 16);
}

// ---------------------------------------------------------------------------
// K0: fp32 -> bf16 for x, mem, fc_w, p2w. One float4 per thread.
// ---------------------------------------------------------------------------
#define X4   (B_ * D_ / 4)
#define MEM4 (C_ * D_ / 4)
#define W4   (TWOD * TWOD / 4)
#define P24  (P_ * TWOD / 4)
#define TOT4 (X4 + MEM4 + W4 + P24)

__global__ __launch_bounds__(256) void prep_bf16(
    const float* __restrict__ x, const float* __restrict__ mem,
    const float* __restrict__ w, const float* __restrict__ p2w,
    ushort* __restrict__ xb, ushort* __restrict__ memb,
    ushort* __restrict__ wb, ushort* __restrict__ p2b)
{
    int i = blockIdx.x * 256 + threadIdx.x;
    if (i >= TOT4) return;
    const float* src; ushort* dst; int off;
    if (i < X4)                  { src = x;   dst = xb;   off = i; }
    else if (i < X4 + MEM4)      { src = mem; dst = memb; off = i - X4; }
    else if (i < X4 + MEM4 + W4) { src = w;   dst = wb;   off = i - X4 - MEM4; }
    else                         { src = p2w; dst = p2b;  off = i - X4 - MEM4 - W4; }
    float4 v = ((const float4*)src)[off];
    ushort4 o;
    o.x = f2bf(v.x); o.y = f2bf(v.y); o.z = f2bf(v.z); o.w = f2bf(v.w);
    ((ushort4*)dst)[off] = o;
}

// ---------------------------------------------------------------------------
// K1: merged MFMA GEMM (x-gemm + mem-gemm in one launch).
// blocks [0,192): xh = x @ Wx^T + fc_b    (64-row tiles x 12 n-tiles)
// blocks [192,228): mh = mem @ Wm^T       (3 m-tiles x 12 n-tiles)
// 64x128 tile, BK=32, 4 waves (2x2 of 32x64), register prefetch.
// ---------------------------------------------------------------------------
__global__ __launch_bounds__(256) void gemm_all(
    const ushort* __restrict__ xbf, const ushort* __restrict__ membf,
    const ushort* __restrict__ wbf, const float* __restrict__ fc_b,
    float* __restrict__ xh, float* __restrict__ mh)
{
    __shared__ ushort As[64 * ASTR];
    __shared__ ushort Bs[128 * ASTR];
    const int id = blockIdx.x;
    const int t  = threadIdx.x;

    const ushort* A; float* Out; int M, m0, n0, koff; bool xblk;
    if (id < 192) {
        xblk = true;  A = xbf;  Out = xh; M = B_;
        m0 = (id & 15) * 64; n0 = (id >> 4) * 128; koff = 0;
    } else {
        int q = id - 192;
        xblk = false; A = membf; Out = mh; M = C_;
        m0 = (q % 3) * 64; n0 = (q / 3) * 128; koff = D_;
    }

    const int wave = t >> 6, lane = t & 63;
    const int wm = (wave & 1) * 32, wn = (wave >> 1) * 64;
    const int fm = lane & 15, quad = lane >> 4;

    const int row_a = t >> 2, qa = (t & 3) * 8;
    const int ar = min(m0 + row_a, M - 1);
    const ushort* Arow = A + (size_t)ar * D_ + qa;
    const ushort* Brow = wbf + (size_t)(n0 + row_a) * TWOD + koff + qa;

    f32x4 acc[2][4];
#pragma unroll
    for (int j = 0; j < 4; ++j) {
        float bv = xblk ? fc_b[n0 + wn + j * 16 + fm] : 0.f;
#pragma unroll
        for (int i = 0; i < 2; ++i)
            acc[i][j] = (f32x4){bv, bv, bv, bv};
    }

    uint4 pa  = *(const uint4*)(Arow);
    uint4 pb0 = *(const uint4*)(Brow);
    uint4 pb1 = *(const uint4*)(Brow + 64 * TWOD);

    for (int k0 = 0; k0 < D_; k0 += 32) {
        __syncthreads();   // prev frag reads done
        *(uint4*)&As[row_a * ASTR + qa] = pa;
        *(uint4*)&Bs[row_a * ASTR + qa] = pb0;
        *(uint4*)&Bs[(64 + row_a) * ASTR + qa] = pb1;
        __syncthreads();
        if (k0 + 32 < D_) {
            pa  = *(const uint4*)(Arow + k0 + 32);
            pb0 = *(const uint4*)(Brow + k0 + 32);
            pb1 = *(const uint4*)(Brow + 64 * TWOD + k0 + 32);
        }
        bfx8 af[2], bf[4];
#pragma unroll
        for (int i = 0; i < 2; ++i)
            af[i] = *(const bfx8*)&As[(wm + i * 16 + fm) * ASTR + quad * 8];
#pragma unroll
        for (int j = 0; j < 4; ++j)
            bf[j] = *(const bfx8*)&Bs[(wn + j * 16 + fm) * ASTR + quad * 8];
#pragma unroll
        for (int i = 0; i < 2; ++i)
#pragma unroll
            for (int j = 0; j < 4; ++j)
                acc[i][j] = __builtin_amdgcn_mfma_f32_16x16x32_bf16(
                    af[i], bf[j], acc[i][j], 0, 0, 0);
    }

#pragma unroll
    for (int i = 0; i < 2; ++i)
#pragma unroll
        for (int j = 0; j < 4; ++j)
#pragma unroll
            for (int r = 0; r < 4; ++r) {
                int row = m0 + wm + i * 16 + quad * 4 + r;
                int col = n0 + wn + j * 16 + fm;
                if (row < M) Out[(size_t)row * TWOD + col] = acc[i][j][r];
            }
}

// ---------------------------------------------------------------------------
// K2: fused tile. y<3: elementwise partial[z][b][c] = sum relu(xh+m)*p1,
// cols 0..191 (151..191 junk, ignored downstream). y==3: MFMA u-projection
// partial[z][b][192+n] = sum_k relu(xh)*p2 (bf16 MFMA), K-chunk z*96.
// ---------------------------------------------------------------------------
__global__ __launch_bounds__(256) void fused_tile(
    const float* __restrict__ xh, const float* __restrict__ mh,
    const float* __restrict__ p1w, const ushort* __restrict__ p2bf,
    float* __restrict__ partial)
{
    __shared__ __align__(16) char smem[46080];
    const int t  = threadIdx.x;
    const int b0 = blockIdx.x * 128;
    const int z  = blockIdx.z;

    if (blockIdx.y == 3) {
        // -------- MFMA u-projection path --------
        ushort* Au = (ushort*)smem;            // 128 x USTRU
        ushort* Wu = (ushort*)(smem + 128 * USTRU * 2);  // 64 x USTRU
        const int kb = z * ECHUNK;
        const int wave = t >> 6, lane = t & 63;
        const int fm = lane & 15, quad = lane >> 4;

        {   // stage relu(xh) -> bf16 : 128 rows x 96 k
            const int row = t >> 1, kh = (t & 1) * 48;
            const float* xr_ = xh + (size_t)(b0 + row) * TWOD + kb + kh;
            ushort tmp[48];
#pragma unroll
            for (int i = 0; i < 12; ++i) {
                float4 v = *(const float4*)&xr_[i * 4];
                tmp[i * 4 + 0] = f2bf(fmaxf(v.x, 0.f));
                tmp[i * 4 + 1] = f2bf(fmaxf(v.y, 0.f));
                tmp[i * 4 + 2] = f2bf(fmaxf(v.z, 0.f));
                tmp[i * 4 + 3] = f2bf(fmaxf(v.w, 0.f));
            }
#pragma unroll
            for (int i = 0; i < 6; ++i)
                *(uint4*)&Au[row * USTRU + kh + i * 8] = *(const uint4*)&tmp[i * 8];
        }
        {   // stage p2 bf16 : 64 rows x 96 k
            const int row = t >> 2, ks = (t & 3) * 24;
            const ushort* pw = p2bf + (size_t)row * TWOD + kb + ks;
#pragma unroll
            for (int i = 0; i < 3; ++i)
                *(uint4*)&Wu[row * USTRU + ks + i * 8] = *(const uint4*)&pw[i * 8];
        }
        __syncthreads();

        f32x4 uacc[2][4];
#pragma unroll
        for (int i = 0; i < 2; ++i)
#pragma unroll
            for (int j = 0; j < 4; ++j) uacc[i][j] = (f32x4){0.f, 0.f, 0.f, 0.f};
#pragma unroll
        for (int k0 = 0; k0 < ECHUNK; k0 += 32) {
            bfx8 af[2], bf[4];
#pragma unroll
            for (int i = 0; i < 2; ++i)
                af[i] = *(const bfx8*)&Au[(wave * 32 + i * 16 + fm) * USTRU + k0 + quad * 8];
#pragma unroll
            for (int j = 0; j < 4; ++j)
                bf[j] = *(const bfx8*)&Wu[(j * 16 + fm) * USTRU + k0 + quad * 8];
#pragma unroll
            for (int i = 0; i < 2; ++i)
#pragma unroll
                for (int j = 0; j < 4; ++j)
                    uacc[i][j] = __builtin_amdgcn_mfma_f32_16x16x32_bf16(
                        af[i], bf[j], uacc[i][j], 0, 0, 0);
        }
#pragma unroll
        for (int i = 0; i < 2; ++i)
#pragma unroll
            for (int j = 0; j < 4; ++j)
#pragma unroll
                for (int r = 0; r < 4; ++r) {
                    int row = b0 + wave * 32 + i * 16 + quad * 4 + r;
                    partial[((size_t)z * B_ + row) * CPAD + 192 + j * 16 + fm] =
                        uacc[i][j][r];
                }
        return;
    }

    // -------- elementwise path: cols c0..c0+63 (c0 in {0,64,128}) --------
    float* xT  = (float*)smem;                       // [ESTEP][128] 16 KB
    float* mT  = (float*)(smem + ESTEP * 128 * 4);   // [ESTEP][64]   8 KB
    float* wT1 = (float*)(smem + ESTEP * 192 * 4);   // [ESTEP]     128 B

    const int c0 = blockIdx.y * 64;
    const int e0 = z * ECHUNK;
    const int tm = t & 15;      // 8 b-rows each
    const int tn = t >> 4;      // 4 c-cols each

    const int xr = t & 127, xh16 = (t >> 7) * 16;      // x: 2 thr/row, 16 e
    const int mc = t & 63,  mq8 = ((t >> 6) & 3) * 8;  // m: 4 thr/col, 8 e
    const int gc = c0 + mc;
    const bool cseen = gc < C_;
    const float* xrow = xh + (size_t)(b0 + xr) * TWOD;
    const float* mrow = mh + (size_t)(cseen ? gc : 0) * TWOD;

    float acc[8][4] = {};

    for (int es = 0; es < ECHUNK; es += ESTEP) {
        const int eb = e0 + es;
        float4 xv[4];
#pragma unroll
        for (int i = 0; i < 4; ++i)
            xv[i] = *(const float4*)&xrow[eb + xh16 + i * 4];
        float4 mv0 = cseen ? *(const float4*)&mrow[eb + mq8]
                           : make_float4(0.f, 0.f, 0.f, 0.f);
        float4 mv1 = cseen ? *(const float4*)&mrow[eb + mq8 + 4]
                           : make_float4(0.f, 0.f, 0.f, 0.f);
        float4 wv = (t < 8) ? *(const float4*)&p1w[eb + t * 4]
                            : make_float4(0.f, 0.f, 0.f, 0.f);
        __syncthreads();   // previous step's LDS reads complete
#pragma unroll
        for (int i = 0; i < 4; ++i) {
            xT[(xh16 + i * 4 + 0) * 128 + xr] = xv[i].x;
            xT[(xh16 + i * 4 + 1) * 128 + xr] = xv[i].y;
            xT[(xh16 + i * 4 + 2) * 128 + xr] = xv[i].z;
            xT[(xh16 + i * 4 + 3) * 128 + xr] = xv[i].w;
        }
        mT[(mq8 + 0) * 64 + mc] = mv0.x; mT[(mq8 + 1) * 64 + mc] = mv0.y;
        mT[(mq8 + 2) * 64 + mc] = mv0.z; mT[(mq8 + 3) * 64 + mc] = mv0.w;
        mT[(mq8 + 4) * 64 + mc] = mv1.x; mT[(mq8 + 5) * 64 + mc] = mv1.y;
        mT[(mq8 + 6) * 64 + mc] = mv1.z; mT[(mq8 + 7) * 64 + mc] = mv1.w;
        if (t < 8) *(float4*)&wT1[t * 4] = wv;
        __syncthreads();

#pragma unroll 4
        for (int e = 0; e < ESTEP; ++e) {
            float a[8], m[4];
            *(float4*)&a[0] = *(const float4*)&xT[e * 128 + tm * 8];
            *(float4*)&a[4] = *(const float4*)&xT[e * 128 + tm * 8 + 4];
            *(float4*)&m[0] = *(const float4*)&mT[e * 64 + tn * 4];
            const float w = wT1[e];
#pragma unroll
            for (int i = 0; i < 8; ++i)
#pragma unroll
                for (int j = 0; j < 4; ++j)
                    acc[i][j] = fmaf(fmaxf(a[i] + m[j], 0.f), w, acc[i][j]);
        }
    }

#pragma unroll
    for (int i = 0; i < 8; ++i) {
        const int gb = b0 + tm * 8 + i;
        float4 v = make_float4(acc[i][0], acc[i][1], acc[i][2], acc[i][3]);
        *(float4*)&partial[((size_t)z * B_ + gb) * CPAD + c0 + tn * 4] = v;
    }
}

// ---------------------------------------------------------------------------
// K3: per-row reduce of partials + bias, u-normalize (-> bf16) + cls loss.
// ---------------------------------------------------------------------------
__global__ __launch_bounds__(256) void reduce_row(
    const float* __restrict__ partial,
    const float* __restrict__ p1b, const float* __restrict__ p2b,
    const int* __restrict__ lb,
    ushort* __restrict__ ubf, float* __restrict__ sqn,
    float* __restrict__ clsbuf)
{
    const int b = blockIdx.x, t = threadIdx.x;
    float v = 0.f;
#pragma unroll
    for (int z = 0; z < ECHUNKS; ++z)
        v += partial[((size_t)z * B_ + b) * CPAD + t];
    if (t < NCLS)       v += p1b[0];
    else if (t >= 192)  v += p2b[t - 192];

    __shared__ float sval[256];
    sval[t] = v;
    __syncthreads();

    if (t < 64) {
        // ---- u normalization (cols 192..255), store bf16 ----
        float uv = sval[192 + t];
        float s = uv * uv;
#pragma unroll
        for (int off = 32; off; off >>= 1) s += __shfl_xor(s, off);
        float inv = 1.f / fmaxf(sqrtf(s), 1e-12f);
        ubf[(size_t)b * P_ + t] = f2bf(uv * inv);
        if (t == 0) sqn[b] = s * inv * inv;

        // ---- classification loss over cols 0..150 ----
        const int l = lb[b];
        float mx = -1e30f;
        for (int j = t; j < NCLS; j += 64)
            if (!(j == l && l < C_)) mx = fmaxf(mx, sval[j]);
#pragma unroll
        for (int off = 32; off; off >>= 1) mx = fmaxf(mx, __shfl_xor(mx, off));
        float se = 0.f;
        for (int j = t; j < NCLS; j += 64)
            if (!(j == l && l < C_)) se += expf(sval[j] - mx);
#pragma unroll
        for (int off = 32; off; off >>= 1) se += __shfl_xor(se, off);

        if (t == 0) {
            float l150  = sval[C_];
            float loss2 = mx + logf(se) - l150;
            float loss1 = 0.f;
            if (l < C_) {
                float a  = sval[l];
                float m2 = fmaxf(a, l150);
                loss1 = m2 - a + logf(expf(a - m2) + expf(l150 - m2));
            }
            clsbuf[b] = loss1 + loss2;
        }
    }
}

// ---------------------------------------------------------------------------
// K4: pairwise margin losses via MFMA Gram tiles. 64x64 pairs per block.
// ---------------------------------------------------------------------------
__global__ __launch_bounds__(256) void pair_loss(
    const ushort* __restrict__ ubf, const float* __restrict__ sqn,
    const int* __restrict__ lb, float* __restrict__ pairpart)
{
    __shared__ ushort ui_s[64 * USTR];
    __shared__ ushort uj_s[64 * USTR];
    __shared__ float sni[64], snj[64];
    __shared__ int   li[64],  lj[64];
    __shared__ float red[4][4];

    const int t  = threadIdx.x;
    const int i0 = blockIdx.x * 64, j0 = blockIdx.y * 64;

    for (int idx = t; idx < 512; idx += 256) {
        int row = idx >> 3, ch = (idx & 7) * 8;
        *(uint4*)&ui_s[row * USTR + ch] =
            *(const uint4*)&ubf[(size_t)(i0 + row) * P_ + ch];
        *(uint4*)&uj_s[row * USTR + ch] =
            *(const uint4*)&ubf[(size_t)(j0 + row) * P_ + ch];
    }
    if (t < 64)       { sni[t] = sqn[i0 + t]; li[t] = lb[i0 + t]; }
    else if (t < 128) { int q = t - 64; snj[q] = sqn[j0 + q]; lj[q] = lb[j0 + q]; }
    __syncthreads();

    const int wave = t >> 6, lane = t & 63;
    const int n = lane & 15, quad = lane >> 4;
    const int iw = wave * 16;

    const bfx8 af0 = *(const bfx8*)&ui_s[(iw + n) * USTR + quad * 8];
    const bfx8 af1 = *(const bfx8*)&ui_s[(iw + n) * USTR + quad * 8 + 32];

    f32x4 acc[4];
#pragma unroll
    for (int jt = 0; jt < 4; ++jt) {
        const bfx8 bf0 = *(const bfx8*)&uj_s[(jt * 16 + n) * USTR + quad * 8];
        const bfx8 bf1 = *(const bfx8*)&uj_s[(jt * 16 + n) * USTR + quad * 8 + 32];
        acc[jt] = __builtin_amdgcn_mfma_f32_16x16x32_bf16(
            af0, bf0, (f32x4){0.f, 0.f, 0.f, 0.f}, 0, 0, 0);
        acc[jt] = __builtin_amdgcn_mfma_f32_16x16x32_bf16(
            af1, bf1, acc[jt], 0, 0, 0);
    }

    float ps = 0.f, pc = 0.f, ns = 0.f, nc = 0.f;
#pragma unroll
    for (int jt = 0; jt < 4; ++jt)
#pragma unroll
        for (int r = 0; r < 4; ++r) {
            const int il = iw + quad * 4 + r;
            const int jl = jt * 16 + n;
            float sq = sni[il] + snj[jl] - 2.f * acc[jt][r];
            float dist = sq > 0.f ? sqrtf(fmaxf(sq, 1e-16f)) : 0.f;
            bool same = (li[il] == lj[jl]);
            if (same) {
                if (i0 + il != j0 + jl) { ps += fmaxf(dist - 0.7f, 0.f); pc += 1.f; }
            } else {
                ns += fmaxf(1.4f - dist, 0.f); nc += 1.f;
            }
        }

#pragma unroll
    for (int off = 32; off; off >>= 1) {
        ps += __shfl_xor(ps, off); pc += __shfl_xor(pc, off);
        ns += __shfl_xor(ns, off); nc += __shfl_xor(nc, off);
    }
    if (lane == 0) { red[0][wave] = ps; red[1][wave] = pc;
                     red[2][wave] = ns; red[3][wave] = nc; }
    __syncthreads();
    if (t == 0) {
        float4 v;
        v.x = red[0][0] + red[0][1] + red[0][2] + red[0][3];
        v.y = red[1][0] + red[1][1] + red[1][2] + red[1][3];
        v.z = red[2][0] + red[2][1] + red[2][2] + red[2][3];
        v.w = red[3][0] + red[3][1] + red[3][2] + red[3][3];
        *(float4*)&pairpart[(size_t)(blockIdx.y * 16 + blockIdx.x) * 4] = v;
    }
}

// ---------------------------------------------------------------------------
// K5: finalize — reduce clsbuf[1024] and pairpart[256][4].
// ---------------------------------------------------------------------------
__global__ __launch_bounds__(256) void finalize(
    const float* __restrict__ clsbuf, const float* __restrict__ pairpart,
    float* __restrict__ out)
{
    __shared__ float red[5][4];
    const int t = threadIdx.x;
    float c = clsbuf[t] + clsbuf[t + 256] + clsbuf[t + 512] + clsbuf[t + 768];
    float4 pp = *(const float4*)&pairpart[(size_t)t * 4];
    float ps = pp.x, pc = pp.y, ns = pp.z, nc = pp.w;
#pragma unroll
    for (int off = 32; off; off >>= 1) {
        c  += __shfl_xor(c, off);
        ps += __shfl_xor(ps, off); pc += __shfl_xor(pc, off);
        ns += __shfl_xor(ns, off); nc += __shfl_xor(nc, off);
    }
    const int wave = t >> 6, lane = t & 63;
    if (lane == 0) { red[0][wave] = c; red[1][wave] = ps; red[2][wave] = pc;
                     red[3][wave] = ns; red[4][wave] = nc; }
    __syncthreads();
    if (t == 0) {
        float C = 0.f, PS = 0.f, PC = 0.f, NS = 0.f, NC = 0.f;
#pragma unroll
        for (int w = 0; w < 4; ++w) {
            C += red[0][w]; PS += red[1][w]; PC += red[2][w];
            NS += red[3][w]; NC += red[4][w];
        }
        out[0] = C / (float)B_ + PS / fmaxf(PC, 1.f) + NS / fmaxf(NC, 1.f);
    }
}

extern "C" void kernel_launch(void* const* d_in, const int* in_sizes, int n_in,
                              void* d_out, int out_size, void* d_ws, size_t ws_size,
                              hipStream_t stream)
{
    const float* x    = (const float*)d_in[0];
    const int*   lb   = (const int*)d_in[1];
    const float* mem  = (const float*)d_in[2];
    const float* fc_w = (const float*)d_in[3];
    const float* fc_b = (const float*)d_in[4];
    const float* p1w  = (const float*)d_in[5];
    const float* p1b  = (const float*)d_in[6];
    const float* p2w  = (const float*)d_in[7];
    const float* p2b  = (const float*)d_in[8];

    float* ws       = (float*)d_ws;
    float* mh       = ws + OFF_MH;
    float* xh       = ws + OFF_XH;
    float* partials = ws + OFF_PARTIAL;
    ushort* ubf     = (ushort*)(ws + OFF_UBF);
    float* sqn      = ws + OFF_SQN;
    float* clsbuf   = ws + OFF_CLS;
    float* pairpart = ws + OFF_PAIR;
    ushort* xbf     = (ushort*)(ws + OFF_XBF);
    ushort* membf   = (ushort*)(ws + OFF_MEMBF);
    ushort* wbf     = (ushort*)(ws + OFF_WBF);
    ushort* p2bf    = (ushort*)(ws + OFF_P2BF);

    // K0: convert x, mem, fc_w, p2w to bf16
    prep_bf16<<<(TOT4 + 255) / 256, 256, 0, stream>>>(x, mem, fc_w, p2w,
                                                      xbf, membf, wbf, p2bf);
    // K1: merged gemms: xh (bias folded) + mh
    gemm_all<<<228, 256, 0, stream>>>(xbf, membf, wbf, fc_b, xh, mh);
    // K2: fused elementwise logits partials + MFMA u-projection partials
    fused_tile<<<dim3(8, 4, ECHUNKS), 256, 0, stream>>>(xh, mh, p1w, p2bf,
                                                        partials);
    // K3: reduce partials + bias, normalize u (bf16), classification loss
    reduce_row<<<B_, 256, 0, stream>>>(partials, p1b, p2b, lb, ubf, sqn, clsbuf);
    // K4: pairwise margin losses
    pair_loss<<<dim3(16, 16), 256, 0, stream>>>(ubf, sqn, lb, pairpart);
    // K5: final reduce + write scalar output
    finalize<<<1, 256, 0, stream>>>(clsbuf, pairpart, (float*)d_out);
}

// Round 8
// 132.167 us; speedup vs baseline: 2.9082x; 1.0889x over previous
//
#include <hip/hip_runtime.h>
#include <math.h>

// Problem constants
#define B_    1024
#define D_    768
#define C_    150
#define P_    64
#define TWOD  1536
#define NCLS  151   // C+1
#define CPAD  256   // partial row: 0..150 logits, 151..191 junk, 192..255 u

// fused_tile: 128b x 64c per block, 8x4/thr, e split 16 ways, whole chunk staged
#define ECHUNKS 16
#define ECHUNK  96

// gemm_all: 64x128 tile, BK=32, bf16 LDS stride 40 (2-way banks)
#define ASTR  40
// u-path LDS stride (halves): 120 -> 240B rows, 16B aligned
#define USTRU 120
// pair_loss LDS stride (halves)
#define USTR  72

// Workspace layout (float offsets)
#define OFF_MH      0                                   // half[150*1536]
#define OFF_XH      (OFF_MH + (C_ * TWOD) / 2)          // half[1024*1536]
#define OFF_PARTIAL (OFF_XH + (B_ * TWOD) / 2)          // fp32[16*1024*256]
#define OFF_UHF     (OFF_PARTIAL + ECHUNKS * B_ * CPAD) // half[1024*64]
#define OFF_SQN     (OFF_UHF + (B_ * P_) / 2)
#define OFF_CLS     (OFF_SQN + B_)
#define OFF_PAIR    (OFF_CLS + B_)
#define OFF_XBF     (OFF_PAIR + 1024)
#define OFF_MEMBF   (OFF_XBF + (B_ * D_) / 2)
#define OFF_WBF     (OFF_MEMBF + (C_ * D_) / 2)
#define OFF_P2H     (OFF_WBF + (TWOD * TWOD) / 2)
#define OFF_P1H     (OFF_P2H + (P_ * TWOD) / 2)
// end ~6.82M floats ~ 27.3 MB

typedef __bf16    bfx8   __attribute__((ext_vector_type(8)));
typedef _Float16  fp16x8 __attribute__((ext_vector_type(8)));
typedef _Float16  h2v    __attribute__((ext_vector_type(2)));
typedef float     f32x4  __attribute__((ext_vector_type(4)));

__device__ inline ushort f2bf(float f) {
    union { float f; unsigned u; } c; c.f = f;
    unsigned r = c.u + 0x7fffu + ((c.u >> 16) & 1u);
    return (ushort)(r >> 16);
}
__device__ inline ushort f2h(float f) {
    _Float16 h = (_Float16)f;
    return __builtin_bit_cast(ushort, h);
}
// s = max(a + m, 0) on packed f16 pairs (v_pk_add_f16 + v_pk_max_f16)
__device__ inline unsigned addrelu2(unsigned a, unsigned m) {
    h2v s = __builtin_bit_cast(h2v, a) + __builtin_bit_cast(h2v, m);
    h2v z = {(_Float16)0.f, (_Float16)0.f};
    s = __builtin_elementwise_max(s, z);
    return __builtin_bit_cast(unsigned, s);
}
__device__ inline unsigned relu2(unsigned a) {
    h2v s = __builtin_bit_cast(h2v, a);
    h2v z = {(_Float16)0.f, (_Float16)0.f};
    s = __builtin_elementwise_max(s, z);
    return __builtin_bit_cast(unsigned, s);
}
// acc += dot(f16pair a, f16pair b) in fp32  (v_dot2_f32_f16)
__device__ inline float dot2acc(unsigned a, unsigned b, float c) {
    return __builtin_amdgcn_fdot2(__builtin_bit_cast(h2v, a),
                                  __builtin_bit_cast(h2v, b), c, false);
}

// ---------------------------------------------------------------------------
// K0: fp32 -> bf16 (x, mem, fc_w) and fp32 -> f16 (p2w, p1w).
// ---------------------------------------------------------------------------
#define X4   (B_ * D_ / 4)
#define MEM4 (C_ * D_ / 4)
#define W4   (TWOD * TWOD / 4)
#define P24  (P_ * TWOD / 4)
#define P14  (TWOD / 4)
#define TOT4 (X4 + MEM4 + W4 + P24 + P14)

__global__ __launch_bounds__(256) void prep_cvt(
    const float* __restrict__ x, const float* __restrict__ mem,
    const float* __restrict__ w, const float* __restrict__ p2w,
    const float* __restrict__ p1w,
    ushort* __restrict__ xb, ushort* __restrict__ memb,
    ushort* __restrict__ wb, ushort* __restrict__ p2h,
    ushort* __restrict__ p1h)
{
    int i = blockIdx.x * 256 + threadIdx.x;
    if (i >= TOT4) return;
    const float* src; ushort* dst; int off; bool bf;
    if (i < X4)                        { src = x;   dst = xb;   off = i; bf = true; }
    else if (i < X4 + MEM4)            { src = mem; dst = memb; off = i - X4; bf = true; }
    else if (i < X4 + MEM4 + W4)       { src = w;   dst = wb;   off = i - X4 - MEM4; bf = true; }
    else if (i < X4 + MEM4 + W4 + P24) { src = p2w; dst = p2h;  off = i - X4 - MEM4 - W4; bf = false; }
    else                               { src = p1w; dst = p1h;  off = i - X4 - MEM4 - W4 - P24; bf = false; }
    float4 v = ((const float4*)src)[off];
    ushort4 o;
    if (bf) { o.x = f2bf(v.x); o.y = f2bf(v.y); o.z = f2bf(v.z); o.w = f2bf(v.w); }
    else    { o.x = f2h(v.x);  o.y = f2h(v.y);  o.z = f2h(v.z);  o.w = f2h(v.w); }
    ((ushort4*)dst)[off] = o;
}

// ---------------------------------------------------------------------------
// K1: merged MFMA GEMM (x-gemm + mem-gemm), f16 outputs.
// blocks [0,192): xh = x @ Wx^T + fc_b ; blocks [192,228): mh = mem @ Wm^T
// 64x128 tile, BK=32, 4 waves (2x2 of 32x64), register prefetch.
// ---------------------------------------------------------------------------
__global__ __launch_bounds__(256) void gemm_all(
    const ushort* __restrict__ xbf, const ushort* __restrict__ membf,
    const ushort* __restrict__ wbf, const float* __restrict__ fc_b,
    ushort* __restrict__ xh, ushort* __restrict__ mh)
{
    __shared__ ushort As[64 * ASTR];
    __shared__ ushort Bs[128 * ASTR];
    const int id = blockIdx.x;
    const int t  = threadIdx.x;

    const ushort* A; ushort* Out; int M, m0, n0, koff; bool xblk;
    if (id < 192) {
        xblk = true;  A = xbf;  Out = xh; M = B_;
        m0 = (id & 15) * 64; n0 = (id >> 4) * 128; koff = 0;
    } else {
        int q = id - 192;
        xblk = false; A = membf; Out = mh; M = C_;
        m0 = (q % 3) * 64; n0 = (q / 3) * 128; koff = D_;
    }

    const int wave = t >> 6, lane = t & 63;
    const int wm = (wave & 1) * 32, wn = (wave >> 1) * 64;
    const int fm = lane & 15, quad = lane >> 4;

    const int row_a = t >> 2, qa = (t & 3) * 8;
    const int ar = min(m0 + row_a, M - 1);
    const ushort* Arow = A + (size_t)ar * D_ + qa;
    const ushort* Brow = wbf + (size_t)(n0 + row_a) * TWOD + koff + qa;

    f32x4 acc[2][4];
#pragma unroll
    for (int j = 0; j < 4; ++j) {
        float bv = xblk ? fc_b[n0 + wn + j * 16 + fm] : 0.f;
#pragma unroll
        for (int i = 0; i < 2; ++i)
            acc[i][j] = (f32x4){bv, bv, bv, bv};
    }

    uint4 pa  = *(const uint4*)(Arow);
    uint4 pb0 = *(const uint4*)(Brow);
    uint4 pb1 = *(const uint4*)(Brow + 64 * TWOD);

    for (int k0 = 0; k0 < D_; k0 += 32) {
        __syncthreads();
        *(uint4*)&As[row_a * ASTR + qa] = pa;
        *(uint4*)&Bs[row_a * ASTR + qa] = pb0;
        *(uint4*)&Bs[(64 + row_a) * ASTR + qa] = pb1;
        __syncthreads();
        if (k0 + 32 < D_) {
            pa  = *(const uint4*)(Arow + k0 + 32);
            pb0 = *(const uint4*)(Brow + k0 + 32);
            pb1 = *(const uint4*)(Brow + 64 * TWOD + k0 + 32);
        }
        bfx8 af[2], bf[4];
#pragma unroll
        for (int i = 0; i < 2; ++i)
            af[i] = *(const bfx8*)&As[(wm + i * 16 + fm) * ASTR + quad * 8];
#pragma unroll
        for (int j = 0; j < 4; ++j)
            bf[j] = *(const bfx8*)&Bs[(wn + j * 16 + fm) * ASTR + quad * 8];
#pragma unroll
        for (int i = 0; i < 2; ++i)
#pragma unroll
            for (int j = 0; j < 4; ++j)
                acc[i][j] = __builtin_amdgcn_mfma_f32_16x16x32_bf16(
                    af[i], bf[j], acc[i][j], 0, 0, 0);
    }

#pragma unroll
    for (int i = 0; i < 2; ++i)
#pragma unroll
        for (int j = 0; j < 4; ++j)
#pragma unroll
            for (int r = 0; r < 4; ++r) {
                int row = m0 + wm + i * 16 + quad * 4 + r;
                int col = n0 + wn + j * 16 + fm;
                if (row < M) Out[(size_t)row * TWOD + col] = f2h(acc[i][j][r]);
            }
}

// ---------------------------------------------------------------------------
// K2: fused tile (f16). y<3: elementwise partial[z][b][c] = sum relu(xh+m)*p1
// via v_pk_add/max_f16 + v_dot2_f32_f16, whole 96-e chunk staged, ONE barrier.
// y==3: MFMA f16 u-projection partial[z][b][192+n] = sum relu(xh)*p2.
// ---------------------------------------------------------------------------
__global__ __launch_bounds__(256) void fused_tile(
    const ushort* __restrict__ xh, const ushort* __restrict__ mh,
    const ushort* __restrict__ p1h, const ushort* __restrict__ p2h,
    float* __restrict__ partial)
{
    __shared__ __align__(16) char smem[46080];
    const int t  = threadIdx.x;
    const int b0 = blockIdx.x * 128;
    const int z  = blockIdx.z;
    const int e0 = z * ECHUNK;

    if (blockIdx.y == 3) {
        // -------- MFMA f16 u-projection path --------
        ushort* Au = (ushort*)smem;                 // 128 x USTRU halves
        ushort* Wu = (ushort*)(smem + 30720);       // 64 x USTRU halves
        const int wave = t >> 6, lane = t & 63;
        const int fm = lane & 15, quad = lane >> 4;

        {   // stage relu(xh) f16 : 128 rows x 96 k
            const int row = t >> 1, kh = (t & 1) * 48;
            const ushort* src = xh + (size_t)(b0 + row) * TWOD + e0 + kh;
            uint4 v[6];
#pragma unroll
            for (int i = 0; i < 6; ++i) v[i] = *(const uint4*)&src[i * 8];
#pragma unroll
            for (int i = 0; i < 6; ++i) {
                v[i].x = relu2(v[i].x); v[i].y = relu2(v[i].y);
                v[i].z = relu2(v[i].z); v[i].w = relu2(v[i].w);
                *(uint4*)&Au[row * USTRU + kh + i * 8] = v[i];
            }
        }
        {   // stage p2 f16 : 64 rows x 96 k
            const int row = t >> 2, ks = (t & 3) * 24;
            const ushort* pw = p2h + (size_t)row * TWOD + e0 + ks;
#pragma unroll
            for (int i = 0; i < 3; ++i)
                *(uint4*)&Wu[row * USTRU + ks + i * 8] = *(const uint4*)&pw[i * 8];
        }
        __syncthreads();

        f32x4 uacc[2][4];
#pragma unroll
        for (int i = 0; i < 2; ++i)
#pragma unroll
            for (int j = 0; j < 4; ++j) uacc[i][j] = (f32x4){0.f, 0.f, 0.f, 0.f};
#pragma unroll
        for (int k0 = 0; k0 < ECHUNK; k0 += 32) {
            fp16x8 af[2], bf[4];
#pragma unroll
            for (int i = 0; i < 2; ++i)
                af[i] = *(const fp16x8*)&Au[(wave * 32 + i * 16 + fm) * USTRU + k0 + quad * 8];
#pragma unroll
            for (int j = 0; j < 4; ++j)
                bf[j] = *(const fp16x8*)&Wu[(j * 16 + fm) * USTRU + k0 + quad * 8];
#pragma unroll
            for (int i = 0; i < 2; ++i)
#pragma unroll
                for (int j = 0; j < 4; ++j)
                    uacc[i][j] = __builtin_amdgcn_mfma_f32_16x16x32_f16(
                        af[i], bf[j], uacc[i][j], 0, 0, 0);
        }
#pragma unroll
        for (int i = 0; i < 2; ++i)
#pragma unroll
            for (int j = 0; j < 4; ++j)
#pragma unroll
                for (int r = 0; r < 4; ++r) {
                    int row = b0 + wave * 32 + i * 16 + quad * 4 + r;
                    partial[((size_t)z * B_ + row) * CPAD + 192 + j * 16 + fm] =
                        uacc[i][j][r];
                }
        return;
    }

    // -------- elementwise f16 path: cols c0..c0+63 (c0 in {0,64,128}) -----
    unsigned* xT = (unsigned*)smem;             // [48 e-pairs][128 b]
    unsigned* mT = (unsigned*)(smem + 24576);   // [48][64 c]
    unsigned* wT = (unsigned*)(smem + 36864);   // [48]
    const int c0 = blockIdx.y * 64;
    const int tm = t & 15, tn = t >> 4;

    {   // stage x: 2 thr/row, 48 halves each
        const int row = t >> 1, ph = (t & 1) * 48;
        const ushort* src = xh + (size_t)(b0 + row) * TWOD + e0 + ph;
        uint4 v[6];
#pragma unroll
        for (int i = 0; i < 6; ++i) v[i] = *(const uint4*)&src[i * 8];
#pragma unroll
        for (int i = 0; i < 6; ++i) {
            const int ep = (t & 1) * 24 + i * 4;
            xT[(ep + 0) * 128 + row] = v[i].x;
            xT[(ep + 1) * 128 + row] = v[i].y;
            xT[(ep + 2) * 128 + row] = v[i].z;
            xT[(ep + 3) * 128 + row] = v[i].w;
        }
    }
    {   // stage m: 4 thr/col, 24 halves each
        const int col = t & 63, seg = t >> 6;
        const int gc  = c0 + col;
        uint4 v[3];
        if (gc < C_) {
            const ushort* src = mh + (size_t)gc * TWOD + e0 + seg * 24;
#pragma unroll
            for (int i = 0; i < 3; ++i) v[i] = *(const uint4*)&src[i * 8];
        } else {
#pragma unroll
            for (int i = 0; i < 3; ++i) v[i] = make_uint4(0, 0, 0, 0);
        }
#pragma unroll
        for (int i = 0; i < 3; ++i) {
            const int ep = seg * 12 + i * 4;
            mT[(ep + 0) * 64 + col] = v[i].x;
            mT[(ep + 1) * 64 + col] = v[i].y;
            mT[(ep + 2) * 64 + col] = v[i].z;
            mT[(ep + 3) * 64 + col] = v[i].w;
        }
    }
    if (t < 12) {  // stage w (p1): 96 halves
        uint4 v = *(const uint4*)&p1h[e0 + t * 8];
        wT[t * 4 + 0] = v.x; wT[t * 4 + 1] = v.y;
        wT[t * 4 + 2] = v.z; wT[t * 4 + 3] = v.w;
    }
    __syncthreads();

    float acc[8][4] = {};
#pragma unroll 4
    for (int ep = 0; ep < 48; ++ep) {
        uint4 a0 = *(const uint4*)&xT[ep * 128 + tm * 8];
        uint4 a1 = *(const uint4*)&xT[ep * 128 + tm * 8 + 4];
        uint4 mj = *(const uint4*)&mT[ep * 64 + tn * 4];
        const unsigned wv = wT[ep];
        const unsigned aa[8] = {a0.x, a0.y, a0.z, a0.w, a1.x, a1.y, a1.z, a1.w};
        const unsigned mm[4] = {mj.x, mj.y, mj.z, mj.w};
#pragma unroll
        for (int i = 0; i < 8; ++i)
#pragma unroll
            for (int j = 0; j < 4; ++j)
                acc[i][j] = dot2acc(addrelu2(aa[i], mm[j]), wv, acc[i][j]);
    }

#pragma unroll
    for (int i = 0; i < 8; ++i) {
        const int gb = b0 + tm * 8 + i;
        float4 v = make_float4(acc[i][0], acc[i][1], acc[i][2], acc[i][3]);
        *(float4*)&partial[((size_t)z * B_ + gb) * CPAD + c0 + tn * 4] = v;
    }
}

// ---------------------------------------------------------------------------
// K3: per-row reduce of partials + bias, u-normalize (-> f16) + cls loss.
// ---------------------------------------------------------------------------
__global__ __launch_bounds__(256) void reduce_row(
    const float* __restrict__ partial,
    const float* __restrict__ p1b, const float* __restrict__ p2b,
    const int* __restrict__ lb,
    ushort* __restrict__ uhf, float* __restrict__ sqn,
    float* __restrict__ clsbuf)
{
    const int b = blockIdx.x, t = threadIdx.x;
    float v = 0.f;
#pragma unroll
    for (int z = 0; z < ECHUNKS; ++z)
        v += partial[((size_t)z * B_ + b) * CPAD + t];
    if (t < NCLS)       v += p1b[0];
    else if (t >= 192)  v += p2b[t - 192];

    __shared__ float sval[256];
    sval[t] = v;
    __syncthreads();

    if (t < 64) {
        float uv = sval[192 + t];
        float s = uv * uv;
#pragma unroll
        for (int off = 32; off; off >>= 1) s += __shfl_xor(s, off);
        float inv = 1.f / fmaxf(sqrtf(s), 1e-12f);
        uhf[(size_t)b * P_ + t] = f2h(uv * inv);
        if (t == 0) sqn[b] = s * inv * inv;

        const int l = lb[b];
        float mx = -1e30f;
        for (int j = t; j < NCLS; j += 64)
            if (!(j == l && l < C_)) mx = fmaxf(mx, sval[j]);
#pragma unroll
        for (int off = 32; off; off >>= 1) mx = fmaxf(mx, __shfl_xor(mx, off));
        float se = 0.f;
        for (int j = t; j < NCLS; j += 64)
            if (!(j == l && l < C_)) se += expf(sval[j] - mx);
#pragma unroll
        for (int off = 32; off; off >>= 1) se += __shfl_xor(se, off);

        if (t == 0) {
            float l150  = sval[C_];
            float loss2 = mx + logf(se) - l150;
            float loss1 = 0.f;
            if (l < C_) {
                float a  = sval[l];
                float m2 = fmaxf(a, l150);
                loss1 = m2 - a + logf(expf(a - m2) + expf(l150 - m2));
            }
            clsbuf[b] = loss1 + loss2;
        }
    }
}

// ---------------------------------------------------------------------------
// K4: pairwise margin losses via f16 MFMA Gram tiles. 64x64 pairs per block.
// ---------------------------------------------------------------------------
__global__ __launch_bounds__(256) void pair_loss(
    const ushort* __restrict__ uhf, const float* __restrict__ sqn,
    const int* __restrict__ lb, float* __restrict__ pairpart)
{
    __shared__ ushort ui_s[64 * USTR];
    __shared__ ushort uj_s[64 * USTR];
    __shared__ float sni[64], snj[64];
    __shared__ int   li[64],  lj[64];
    __shared__ float red[4][4];

    const int t  = threadIdx.x;
    const int i0 = blockIdx.x * 64, j0 = blockIdx.y * 64;

    for (int idx = t; idx < 512; idx += 256) {
        int row = idx >> 3, ch = (idx & 7) * 8;
        *(uint4*)&ui_s[row * USTR + ch] =
            *(const uint4*)&uhf[(size_t)(i0 + row) * P_ + ch];
        *(uint4*)&uj_s[row * USTR + ch] =
            *(const uint4*)&uhf[(size_t)(j0 + row) * P_ + ch];
    }
    if (t < 64)       { sni[t] = sqn[i0 + t]; li[t] = lb[i0 + t]; }
    else if (t < 128) { int q = t - 64; snj[q] = sqn[j0 + q]; lj[q] = lb[j0 + q]; }
    __syncthreads();

    const int wave = t >> 6, lane = t & 63;
    const int n = lane & 15, quad = lane >> 4;
    const int iw = wave * 16;

    const fp16x8 af0 = *(const fp16x8*)&ui_s[(iw + n) * USTR + quad * 8];
    const fp16x8 af1 = *(const fp16x8*)&ui_s[(iw + n) * USTR + quad * 8 + 32];

    f32x4 acc[4];
#pragma unroll
    for (int jt = 0; jt < 4; ++jt) {
        const fp16x8 bf0 = *(const fp16x8*)&uj_s[(jt * 16 + n) * USTR + quad * 8];
        const fp16x8 bf1 = *(const fp16x8*)&uj_s[(jt * 16 + n) * USTR + quad * 8 + 32];
        acc[jt] = __builtin_amdgcn_mfma_f32_16x16x32_f16(
            af0, bf0, (f32x4){0.f, 0.f, 0.f, 0.f}, 0, 0, 0);
        acc[jt] = __builtin_amdgcn_mfma_f32_16x16x32_f16(
            af1, bf1, acc[jt], 0, 0, 0);
    }

    float ps = 0.f, pc = 0.f, ns = 0.f, nc = 0.f;
#pragma unroll
    for (int jt = 0; jt < 4; ++jt)
#pragma unroll
        for (int r = 0; r < 4; ++r) {
            const int il = iw + quad * 4 + r;
            const int jl = jt * 16 + n;
            float sq = sni[il] + snj[jl] - 2.f * acc[jt][r];
            float dist = sq > 0.f ? sqrtf(fmaxf(sq, 1e-16f)) : 0.f;
            bool same = (li[il] == lj[jl]);
            if (same) {
                if (i0 + il != j0 + jl) { ps += fmaxf(dist - 0.7f, 0.f); pc += 1.f; }
            } else {
                ns += fmaxf(1.4f - dist, 0.f); nc += 1.f;
            }
        }

#pragma unroll
    for (int off = 32; off; off >>= 1) {
        ps += __shfl_xor(ps, off); pc += __shfl_xor(pc, off);
        ns += __shfl_xor(ns, off); nc += __shfl_xor(nc, off);
    }
    if (lane == 0) { red[0][wave] = ps; red[1][wave] = pc;
                     red[2][wave] = ns; red[3][wave] = nc; }
    __syncthreads();
    if (t == 0) {
        float4 v;
        v.x = red[0][0] + red[0][1] + red[0][2] + red[0][3];
        v.y = red[1][0] + red[1][1] + red[1][2] + red[1][3];
        v.z = red[2][0] + red[2][1] + red[2][2] + red[2][3];
        v.w = red[3][0] + red[3][1] + red[3][2] + red[3][3];
        *(float4*)&pairpart[(size_t)(blockIdx.y * 16 + blockIdx.x) * 4] = v;
    }
}

// ---------------------------------------------------------------------------
// K5: finalize — reduce clsbuf[1024] and pairpart[256][4].
// ---------------------------------------------------------------------------
__global__ __launch_bounds__(256) void finalize(
    const float* __restrict__ clsbuf, const float* __restrict__ pairpart,
    float* __restrict__ out)
{
    __shared__ float red[5][4];
    const int t = threadIdx.x;
    float c = clsbuf[t] + clsbuf[t + 256] + clsbuf[t + 512] + clsbuf[t + 768];
    float4 pp = *(const float4*)&pairpart[(size_t)t * 4];
    float ps = pp.x, pc = pp.y, ns = pp.z, nc = pp.w;
#pragma unroll
    for (int off = 32; off; off >>= 1) {
        c  += __shfl_xor(c, off);
        ps += __shfl_xor(ps, off); pc += __shfl_xor(pc, off);
        ns += __shfl_xor(ns, off); nc += __shfl_xor(nc, off);
    }
    const int wave = t >> 6, lane = t & 63;
    if (lane == 0) { red[0][wave] = c; red[1][wave] = ps; red[2][wave] = pc;
                     red[3][wave] = ns; red[4][wave] = nc; }
    __syncthreads();
    if (t == 0) {
        float C = 0.f, PS = 0.f, PC = 0.f, NS = 0.f, NC = 0.f;
#pragma unroll
        for (int w = 0; w < 4; ++w) {
            C += red[0][w]; PS += red[1][w]; PC += red[2][w];
            NS += red[3][w]; NC += red[4][w];
        }
        out[0] = C / (float)B_ + PS / fmaxf(PC, 1.f) + NS / fmaxf(NC, 1.f);
    }
}

extern "C" void kernel_launch(void* const* d_in, const int* in_sizes, int n_in,
                              void* d_out, int out_size, void* d_ws, size_t ws_size,
                              hipStream_t stream)
{
    const float* x    = (const float*)d_in[0];
    const int*   lb   = (const int*)d_in[1];
    const float* mem  = (const float*)d_in[2];
    const float* fc_w = (const float*)d_in[3];
    const float* fc_b = (const float*)d_in[4];
    const float* p1w  = (const float*)d_in[5];
    const float* p1b  = (const float*)d_in[6];
    const float* p2w  = (const float*)d_in[7];
    const float* p2b  = (const float*)d_in[8];

    float* ws       = (float*)d_ws;
    ushort* mh      = (ushort*)(ws + OFF_MH);
    ushort* xh      = (ushort*)(ws + OFF_XH);
    float* partials = ws + OFF_PARTIAL;
    ushort* uhf     = (ushort*)(ws + OFF_UHF);
    float* sqn      = ws + OFF_SQN;
    float* clsbuf   = ws + OFF_CLS;
    float* pairpart = ws + OFF_PAIR;
    ushort* xbf     = (ushort*)(ws + OFF_XBF);
    ushort* membf   = (ushort*)(ws + OFF_MEMBF);
    ushort* wbf     = (ushort*)(ws + OFF_WBF);
    ushort* p2h     = (ushort*)(ws + OFF_P2H);
    ushort* p1h     = (ushort*)(ws + OFF_P1H);

    // K0: dtype conversions
    prep_cvt<<<(TOT4 + 255) / 256, 256, 0, stream>>>(x, mem, fc_w, p2w, p1w,
                                                     xbf, membf, wbf, p2h, p1h);
    // K1: merged gemms -> f16 xh (bias folded), f16 mh
    gemm_all<<<228, 256, 0, stream>>>(xbf, membf, wbf, fc_b, xh, mh);
    // K2: fused elementwise logits partials (f16 dot2) + MFMA f16 u-partials
    fused_tile<<<dim3(8, 4, ECHUNKS), 256, 0, stream>>>(xh, mh, p1h, p2h,
                                                        partials);
    // K3: reduce partials + bias, normalize u (f16), classification loss
    reduce_row<<<B_, 256, 0, stream>>>(partials, p1b, p2b, lb, uhf, sqn, clsbuf);
    // K4: pairwise margin losses
    pair_loss<<<dim3(16, 16), 256, 0, stream>>>(uhf, sqn, lb, pairpart);
    // K5: final reduce + write scalar output
    finalize<<<1, 256, 0, stream>>>(clsbuf, pairpart, (float*)d_out);
}